// Round 1
// baseline (304.829 us; speedup 1.0000x reference)
//
#include <hip/hip_runtime.h>
#include <hip/hip_bf16.h>
#include <stdint.h>

typedef float f32x4 __attribute__((ext_vector_type(4)));
typedef float f32x4v __attribute__((ext_vector_type(4)));
typedef __bf16 bf16x8 __attribute__((ext_vector_type(8)));
typedef __bf16 bf16x4 __attribute__((ext_vector_type(4)));

#define LOG2E 1.44269504088896340736f
#define MFMA16(a, b, c) __builtin_amdgcn_mfma_f32_16x16x32_bf16((a), (b), (c), 0, 0, 0)

static __device__ __forceinline__ void gload_lds16(const void* g, void* l) {
  __builtin_amdgcn_global_load_lds(
      (const __attribute__((address_space(1))) unsigned int*)g,
      (__attribute__((address_space(3))) unsigned int*)l, 16, 0, 0);
}

// ---------------------------------------------------------------- converts
__global__ __launch_bounds__(256) void cvt_f32_bf16(const float* __restrict__ in,
                                                    __bf16* __restrict__ out) {
  int i = blockIdx.x * 256 + threadIdx.x;
  f32x4v v = *(const f32x4v*)(in + (size_t)i * 4);
  bf16x4 o;
  o[0] = (__bf16)v[0]; o[1] = (__bf16)v[1]; o[2] = (__bf16)v[2]; o[3] = (__bf16)v[3];
  *(bf16x4*)(out + (size_t)i * 4) = o;
}

// in [R][C] f32 -> out [C][R] bf16, 64x64 tiles
__global__ __launch_bounds__(256) void transpose_f32_bf16(const float* __restrict__ in,
                                                          __bf16* __restrict__ out,
                                                          int R, int C) {
  __shared__ float tile[64][65];
  int tr = blockIdx.y * 64, tc = blockIdx.x * 64;
  int t = threadIdx.x;
  int r0 = t >> 4;            // 0..15
  int c4 = (t & 15) * 4;      // 0..60
#pragma unroll
  for (int i = 0; i < 4; ++i) {
    int r = r0 + i * 16;
    f32x4v v = *(const f32x4v*)(in + (size_t)(tr + r) * C + tc + c4);
    tile[r][c4 + 0] = v[0]; tile[r][c4 + 1] = v[1];
    tile[r][c4 + 2] = v[2]; tile[r][c4 + 3] = v[3];
  }
  __syncthreads();
#pragma unroll
  for (int i = 0; i < 4; ++i) {
    int r = r0 + i * 16;     // out-row within tile (global col tc+r)
    __bf16* o = out + (size_t)(tc + r) * R + tr + c4;
    bf16x4 ov;
    ov[0] = (__bf16)tile[c4 + 0][r]; ov[1] = (__bf16)tile[c4 + 1][r];
    ov[2] = (__bf16)tile[c4 + 2][r]; ov[3] = (__bf16)tile[c4 + 3][r];
    *(bf16x4*)o = ov;
  }
}

// ---------------------------------------------------------------- GEMM (m97-style)
// C[M][N] = A[M][K] * B  with B given transposed: BT[N][K]. 128x128 tile, BK=32.
template <typename OutT>
__global__ __launch_bounds__(256) void gemm_bt(const __bf16* __restrict__ A,
                                               const __bf16* __restrict__ BT,
                                               OutT* __restrict__ C,
                                               int M, int N, int K) {
  __shared__ alignas(16) __bf16 As[128 * 32];
  __shared__ alignas(16) __bf16 Bs[128 * 32];
  int bn = blockIdx.x, bm = blockIdx.y;
  int t = threadIdx.x;
  int lane = t & 63, w = t >> 6;
  int lmod = lane & 15, ldiv = lane >> 4;
  int wr = w >> 1, wc = w & 1;

  f32x4 acc[4][4] = {};

  // staging: wave w handles 1KB chunks c=w and c=w+4 of each 8KB buffer.
  // LDS linear [row][k], 64B rows. chunk c: rows c*16 + lane/4, kcol (lane&3)*8
  int srow = lane >> 2;
  int scol = (lane & 3) * 8;
  const __bf16* ga0 = A + (size_t)(bm * 128 + w * 16 + srow) * K + scol;
  const __bf16* ga1 = A + (size_t)(bm * 128 + (w + 4) * 16 + srow) * K + scol;
  const __bf16* gb0 = BT + (size_t)(bn * 128 + w * 16 + srow) * K + scol;
  const __bf16* gb1 = BT + (size_t)(bn * 128 + (w + 4) * 16 + srow) * K + scol;
  __bf16* la0 = As + w * 512;
  __bf16* la1 = As + (w + 4) * 512;
  __bf16* lb0 = Bs + w * 512;
  __bf16* lb1 = Bs + (w + 4) * 512;

  for (int k0 = 0; k0 < K; k0 += 32) {
    __syncthreads();
    gload_lds16(ga0 + k0, la0);
    gload_lds16(ga1 + k0, la1);
    gload_lds16(gb0 + k0, lb0);
    gload_lds16(gb1 + k0, lb1);
    __syncthreads();
    bf16x8 af[4], bfr[4];
#pragma unroll
    for (int i = 0; i < 4; ++i)
      af[i] = *(const bf16x8*)(As + (wr * 64 + i * 16 + lmod) * 32 + ldiv * 8);
#pragma unroll
    for (int i = 0; i < 4; ++i)
      bfr[i] = *(const bf16x8*)(Bs + (wc * 64 + i * 16 + lmod) * 32 + ldiv * 8);
#pragma unroll
    for (int i = 0; i < 4; ++i)
#pragma unroll
      for (int j = 0; j < 4; ++j)
        acc[i][j] = MFMA16(af[i], bfr[j], acc[i][j]);
  }

#pragma unroll
  for (int i = 0; i < 4; ++i) {
    int row0 = bm * 128 + wr * 64 + i * 16 + ldiv * 4;
#pragma unroll
    for (int j = 0; j < 4; ++j) {
      int col = bn * 128 + wc * 64 + j * 16 + lmod;
#pragma unroll
      for (int r = 0; r < 4; ++r)
        C[(size_t)(row0 + r) * N + col] = (OutT)acc[i][j][r];
    }
  }
}

// ---------------------------------------------------------------- RoPE + restructure
// qkv [2048][3072] bf16 (in/out, Q roped in place)
// Kr  [8][2048][64] bf16 (roped)
// Vt  [8][64][2048] bf16 (transposed)
__global__ __launch_bounds__(256) void rope_restruct(__bf16* __restrict__ qkv,
                                                     const float* __restrict__ cosb,
                                                     const float* __restrict__ sinb,
                                                     __bf16* __restrict__ Kr,
                                                     __bf16* __restrict__ Vt) {
  int st = blockIdx.x * 64;
  int kvh = blockIdx.y;
  int t = threadIdx.x;
  __shared__ alignas(16) __bf16 vtile[64][72];

  int r = t >> 2;
  int q4 = t & 3;
  int s = st + r;
  const float* cp = cosb + (size_t)s * 32;
  const float* sp = sinb + (size_t)s * 32;

  // Q rope in place, head h = kvh*4 + q4
  {
    __bf16* p = qkv + (size_t)s * 3072 + (kvh * 4 + q4) * 64;
#pragma unroll
    for (int d = 0; d < 16; ++d) {
      float x1 = (float)p[d], x2 = (float)p[d + 16];
      float o1 = x1 * cp[d] - x2 * sp[d];
      float o2 = x2 * cp[d + 16] + x1 * sp[d + 16];
      p[d] = (__bf16)o1;
      p[d + 16] = (__bf16)o2;
    }
  }
  // K rope -> Kr
  {
    const __bf16* p = qkv + (size_t)s * 3072 + 2048 + kvh * 64;
    __bf16* ko = Kr + ((size_t)kvh * 2048 + s) * 64;
    if (q4 == 0) {
#pragma unroll
      for (int d = 0; d < 16; ++d) {
        float x1 = (float)p[d], x2 = (float)p[d + 16];
        ko[d] = (__bf16)(x1 * cp[d] - x2 * sp[d]);
      }
    } else if (q4 == 1) {
#pragma unroll
      for (int d = 0; d < 16; ++d) {
        float x1 = (float)p[d], x2 = (float)p[d + 16];
        ko[d + 16] = (__bf16)(x2 * cp[d + 16] + x1 * sp[d + 16]);
      }
    } else if (q4 == 2) {
      *(bf16x8*)(ko + 32) = *(const bf16x8*)(p + 32);
      *(bf16x8*)(ko + 40) = *(const bf16x8*)(p + 40);
    } else {
      *(bf16x8*)(ko + 48) = *(const bf16x8*)(p + 48);
      *(bf16x8*)(ko + 56) = *(const bf16x8*)(p + 56);
    }
  }
  // V transpose -> Vt
  {
    const __bf16* p = qkv + (size_t)s * 3072 + 2560 + kvh * 64 + q4 * 16;
    *(bf16x8*)&vtile[r][q4 * 16] = *(const bf16x8*)p;
    *(bf16x8*)&vtile[r][q4 * 16 + 8] = *(const bf16x8*)(p + 8);
  }
  __syncthreads();
  {
    int d = t >> 2;
    __bf16* vo = Vt + ((size_t)kvh * 64 + d) * 2048 + st + q4 * 16;
#pragma unroll
    for (int j = 0; j < 16; ++j) vo[j] = vtile[q4 * 16 + j][d];
  }
}

// ---------------------------------------------------------------- flash attention
// O [2048][2048] bf16 (s, h*64+d). 4 waves x 16 q-rows, KV tile = 32.
__global__ __launch_bounds__(256) void attn_fwd(const __bf16* __restrict__ qkv,
                                                const __bf16* __restrict__ Kr,
                                                const __bf16* __restrict__ Vt,
                                                __bf16* __restrict__ O) {
  const int S = 2048, LDQ = 3072;
  int qt = 31 - blockIdx.x;   // longest blocks first
  int h = blockIdx.y;
  int kvh = h >> 2;
  int t = threadIdx.x;
  int lane = t & 63, w = t >> 6;
  int lmod = lane & 15, ldiv = lane >> 4;

  __shared__ alignas(16) __bf16 Ks[32][72];
  __shared__ alignas(16) __bf16 Vs[64][40];
  __shared__ alignas(16) __bf16 Ps[4][16][40];

  int qrow = qt * 64 + w * 16 + lmod;
  const __bf16* qp = qkv + (size_t)qrow * LDQ + h * 64;
  bf16x8 qa0 = *(const bf16x8*)(qp + ldiv * 8);
  bf16x8 qa1 = *(const bf16x8*)(qp + 32 + ldiv * 8);

  f32x4 acc[4] = {};
  float m_r[4], l_r[4];
#pragma unroll
  for (int r = 0; r < 4; ++r) { m_r[r] = -1e30f; l_r[r] = 0.f; }

  int rowbase = qt * 64 + w * 16 + ldiv * 4;
  int nkt = 2 * qt + 2;
  const __bf16* kg = Kr + (size_t)kvh * S * 64 + (size_t)(t >> 3) * 64 + (t & 7) * 8;
  const __bf16* vg = Vt + ((size_t)kvh * 64 + (t >> 2)) * S + (t & 3) * 8;

  for (int kt = 0; kt < nkt; ++kt) {
    int ks = kt * 32;
    __syncthreads();
    *(bf16x8*)&Ks[t >> 3][(t & 7) * 8] = *(const bf16x8*)(kg + (size_t)ks * 64);
    *(bf16x8*)&Vs[t >> 2][(t & 3) * 8] = *(const bf16x8*)(vg + ks);
    __syncthreads();

    f32x4 s0 = {}, s1 = {};
    bf16x8 k00 = *(const bf16x8*)&Ks[lmod][ldiv * 8];
    bf16x8 k01 = *(const bf16x8*)&Ks[lmod][32 + ldiv * 8];
    s0 = MFMA16(qa0, k00, s0);
    s0 = MFMA16(qa1, k01, s0);
    bf16x8 k10 = *(const bf16x8*)&Ks[16 + lmod][ldiv * 8];
    bf16x8 k11 = *(const bf16x8*)&Ks[16 + lmod][32 + ldiv * 8];
    s1 = MFMA16(qa0, k10, s1);
    s1 = MFMA16(qa1, k11, s1);

    float a0[4], a1[4], pm[4];
#pragma unroll
    for (int r = 0; r < 4; ++r) {
      int row = rowbase + r;
      a0[r] = (ks + lmod) <= row ? s0[r] * 0.125f : -1e30f;
      a1[r] = (ks + 16 + lmod) <= row ? s1[r] * 0.125f : -1e30f;
      pm[r] = fmaxf(a0[r], a1[r]);
    }
#pragma unroll
    for (int off = 1; off < 16; off <<= 1)
#pragma unroll
      for (int r = 0; r < 4; ++r) pm[r] = fmaxf(pm[r], __shfl_xor(pm[r], off));

    float p0[4], p1[4], al[4], rs[4];
#pragma unroll
    for (int r = 0; r < 4; ++r) {
      float nm = fmaxf(m_r[r], pm[r]);
      al[r] = exp2f((m_r[r] - nm) * LOG2E);
      p0[r] = exp2f((a0[r] - nm) * LOG2E);
      p1[r] = exp2f((a1[r] - nm) * LOG2E);
      rs[r] = p0[r] + p1[r];
      m_r[r] = nm;
    }
#pragma unroll
    for (int off = 1; off < 16; off <<= 1)
#pragma unroll
      for (int r = 0; r < 4; ++r) rs[r] += __shfl_xor(rs[r], off);
#pragma unroll
    for (int r = 0; r < 4; ++r) l_r[r] = l_r[r] * al[r] + rs[r];
#pragma unroll
    for (int g = 0; g < 4; ++g)
#pragma unroll
      for (int r = 0; r < 4; ++r) acc[g][r] *= al[r];

#pragma unroll
    for (int r = 0; r < 4; ++r) {
      Ps[w][ldiv * 4 + r][lmod] = (__bf16)p0[r];
      Ps[w][ldiv * 4 + r][16 + lmod] = (__bf16)p1[r];
    }
    __syncthreads();
    bf16x8 pa = *(const bf16x8*)&Ps[w][lmod][ldiv * 8];
#pragma unroll
    for (int g = 0; g < 4; ++g) {
      bf16x8 vb = *(const bf16x8*)&Vs[g * 16 + lmod][ldiv * 8];
      acc[g] = MFMA16(pa, vb, acc[g]);
    }
  }

#pragma unroll
  for (int g = 0; g < 4; ++g)
#pragma unroll
    for (int r = 0; r < 4; ++r)
      O[(size_t)(rowbase + r) * 2048 + h * 64 + g * 16 + lmod] =
          (__bf16)(acc[g][r] / l_r[r]);
}

// ---------------------------------------------------------------- launch
extern "C" void kernel_launch(void* const* d_in, const int* in_sizes, int n_in,
                              void* d_out, int out_size, void* d_ws, size_t ws_size,
                              hipStream_t stream) {
  const float* x = (const float*)d_in[0];
  const float* cosb = (const float*)d_in[1];
  const float* sinb = (const float*)d_in[2];
  const float* wqkv = (const float*)d_in[3];
  const float* wo = (const float*)d_in[4];
  float* out = (float*)d_out;

  char* ws = (char*)d_ws;
  __bf16* xb    = (__bf16*)(ws + 0);          //  8,388,608
  __bf16* wqkvT = (__bf16*)(ws + 8388608);    // 12,582,912
  __bf16* woT   = (__bf16*)(ws + 20971520);   //  8,388,608
  __bf16* qkvb  = (__bf16*)(ws + 29360128);   // 12,582,912
  __bf16* Krb   = (__bf16*)(ws + 41943040);   //  2,097,152
  __bf16* Vtb   = (__bf16*)(ws + 44040192);   //  2,097,152
  __bf16* attnb = (__bf16*)(ws + 46137344);   //  8,388,608

  cvt_f32_bf16<<<4096, 256, 0, stream>>>(x, xb);
  transpose_f32_bf16<<<dim3(48, 32), 256, 0, stream>>>(wqkv, wqkvT, 2048, 3072);
  transpose_f32_bf16<<<dim3(32, 32), 256, 0, stream>>>(wo, woT, 2048, 2048);
  gemm_bt<__bf16><<<dim3(24, 16), 256, 0, stream>>>(xb, wqkvT, qkvb, 2048, 3072, 2048);
  rope_restruct<<<dim3(32, 8), 256, 0, stream>>>(qkvb, cosb, sinb, Krb, Vtb);
  attn_fwd<<<dim3(32, 32), 256, 0, stream>>>(qkvb, Krb, Vtb, attnb);
  gemm_bt<float><<<dim3(16, 16), 256, 0, stream>>>(attnb, woT, out, 2048, 2048, 2048);
}

// Round 2
// 217.236 us; speedup vs baseline: 1.4032x; 1.4032x over previous
//
#include <hip/hip_runtime.h>
#include <hip/hip_bf16.h>
#include <stdint.h>

typedef float f32x4 __attribute__((ext_vector_type(4)));
typedef float f32x4v __attribute__((ext_vector_type(4)));
typedef __bf16 bf16x8 __attribute__((ext_vector_type(8)));
typedef __bf16 bf16x4 __attribute__((ext_vector_type(4)));
typedef __bf16 bf16x2 __attribute__((ext_vector_type(2)));
typedef unsigned int u32x4 __attribute__((ext_vector_type(4)));

#define LOG2E 1.44269504088896340736f
#define MFMA16(a, b, c) __builtin_amdgcn_mfma_f32_16x16x32_bf16((a), (b), (c), 0, 0, 0)

static __device__ __forceinline__ void gload_lds16(const void* g, void* l) {
  __builtin_amdgcn_global_load_lds(
      (const __attribute__((address_space(1))) unsigned int*)g,
      (__attribute__((address_space(3))) unsigned int*)l, 16, 0, 0);
}

static __device__ __forceinline__ uint32_t pk2(float lo, float hi) {
  bf16x2 v;
  v[0] = (__bf16)lo;
  v[1] = (__bf16)hi;
  return __builtin_bit_cast(uint32_t, v);
}

// ---------------------------------------------------------------- converts
__global__ __launch_bounds__(256) void cvt_f32_bf16(const float* __restrict__ in,
                                                    __bf16* __restrict__ out) {
  int i = blockIdx.x * 256 + threadIdx.x;
  f32x4v v = *(const f32x4v*)(in + (size_t)i * 4);
  bf16x4 o;
  o[0] = (__bf16)v[0]; o[1] = (__bf16)v[1]; o[2] = (__bf16)v[2]; o[3] = (__bf16)v[3];
  *(bf16x4*)(out + (size_t)i * 4) = o;
}

// in [R][C] f32 -> out [C][R] bf16, 64x64 tiles
__global__ __launch_bounds__(256) void transpose_f32_bf16(const float* __restrict__ in,
                                                          __bf16* __restrict__ out,
                                                          int R, int C) {
  __shared__ float tile[64][65];
  int tr = blockIdx.y * 64, tc = blockIdx.x * 64;
  int t = threadIdx.x;
  int r0 = t >> 4;
  int c4 = (t & 15) * 4;
#pragma unroll
  for (int i = 0; i < 4; ++i) {
    int r = r0 + i * 16;
    f32x4v v = *(const f32x4v*)(in + (size_t)(tr + r) * C + tc + c4);
    tile[r][c4 + 0] = v[0]; tile[r][c4 + 1] = v[1];
    tile[r][c4 + 2] = v[2]; tile[r][c4 + 3] = v[3];
  }
  __syncthreads();
#pragma unroll
  for (int i = 0; i < 4; ++i) {
    int r = r0 + i * 16;
    __bf16* o = out + (size_t)(tc + r) * R + tr + c4;
    bf16x4 ov;
    ov[0] = (__bf16)tile[c4 + 0][r]; ov[1] = (__bf16)tile[c4 + 1][r];
    ov[2] = (__bf16)tile[c4 + 2][r]; ov[3] = (__bf16)tile[c4 + 3][r];
    *(bf16x4*)o = ov;
  }
}

// ---------------------------------------------------------------- GEMM (m97-style)
template <typename OutT>
__global__ __launch_bounds__(256) void gemm_bt(const __bf16* __restrict__ A,
                                               const __bf16* __restrict__ BT,
                                               OutT* __restrict__ C,
                                               int M, int N, int K) {
  __shared__ alignas(16) __bf16 As[128 * 32];
  __shared__ alignas(16) __bf16 Bs[128 * 32];
  int bn = blockIdx.x, bm = blockIdx.y;
  int t = threadIdx.x;
  int lane = t & 63, w = t >> 6;
  int lmod = lane & 15, ldiv = lane >> 4;
  int wr = w >> 1, wc = w & 1;

  f32x4 acc[4][4] = {};

  int srow = lane >> 2;
  int scol = (lane & 3) * 8;
  const __bf16* ga0 = A + (size_t)(bm * 128 + w * 16 + srow) * K + scol;
  const __bf16* ga1 = A + (size_t)(bm * 128 + (w + 4) * 16 + srow) * K + scol;
  const __bf16* gb0 = BT + (size_t)(bn * 128 + w * 16 + srow) * K + scol;
  const __bf16* gb1 = BT + (size_t)(bn * 128 + (w + 4) * 16 + srow) * K + scol;
  __bf16* la0 = As + w * 512;
  __bf16* la1 = As + (w + 4) * 512;
  __bf16* lb0 = Bs + w * 512;
  __bf16* lb1 = Bs + (w + 4) * 512;

  for (int k0 = 0; k0 < K; k0 += 32) {
    __syncthreads();
    gload_lds16(ga0 + k0, la0);
    gload_lds16(ga1 + k0, la1);
    gload_lds16(gb0 + k0, lb0);
    gload_lds16(gb1 + k0, lb1);
    __syncthreads();
    bf16x8 af[4], bfr[4];
#pragma unroll
    for (int i = 0; i < 4; ++i)
      af[i] = *(const bf16x8*)(As + (wr * 64 + i * 16 + lmod) * 32 + ldiv * 8);
#pragma unroll
    for (int i = 0; i < 4; ++i)
      bfr[i] = *(const bf16x8*)(Bs + (wc * 64 + i * 16 + lmod) * 32 + ldiv * 8);
#pragma unroll
    for (int i = 0; i < 4; ++i)
#pragma unroll
      for (int j = 0; j < 4; ++j)
        acc[i][j] = MFMA16(af[i], bfr[j], acc[i][j]);
  }

#pragma unroll
  for (int i = 0; i < 4; ++i) {
    int row0 = bm * 128 + wr * 64 + i * 16 + ldiv * 4;
#pragma unroll
    for (int j = 0; j < 4; ++j) {
      int col = bn * 128 + wc * 64 + j * 16 + lmod;
#pragma unroll
      for (int r = 0; r < 4; ++r)
        C[(size_t)(row0 + r) * N + col] = (OutT)acc[i][j][r];
    }
  }
}

// ---------------------------------------------------------------- RoPE + restructure
__global__ __launch_bounds__(256) void rope_restruct(__bf16* __restrict__ qkv,
                                                     const float* __restrict__ cosb,
                                                     const float* __restrict__ sinb,
                                                     __bf16* __restrict__ Kr,
                                                     __bf16* __restrict__ Vt) {
  int st = blockIdx.x * 64;
  int kvh = blockIdx.y;
  int t = threadIdx.x;
  __shared__ alignas(16) __bf16 vtile[64][72];

  int r = t >> 2;
  int q4 = t & 3;
  int s = st + r;
  const float* cp = cosb + (size_t)s * 32;
  const float* sp = sinb + (size_t)s * 32;

  {
    __bf16* p = qkv + (size_t)s * 3072 + (kvh * 4 + q4) * 64;
#pragma unroll
    for (int d = 0; d < 16; ++d) {
      float x1 = (float)p[d], x2 = (float)p[d + 16];
      float o1 = x1 * cp[d] - x2 * sp[d];
      float o2 = x2 * cp[d + 16] + x1 * sp[d + 16];
      p[d] = (__bf16)o1;
      p[d + 16] = (__bf16)o2;
    }
  }
  {
    const __bf16* p = qkv + (size_t)s * 3072 + 2048 + kvh * 64;
    __bf16* ko = Kr + ((size_t)kvh * 2048 + s) * 64;
    if (q4 == 0) {
#pragma unroll
      for (int d = 0; d < 16; ++d) {
        float x1 = (float)p[d], x2 = (float)p[d + 16];
        ko[d] = (__bf16)(x1 * cp[d] - x2 * sp[d]);
      }
    } else if (q4 == 1) {
#pragma unroll
      for (int d = 0; d < 16; ++d) {
        float x1 = (float)p[d], x2 = (float)p[d + 16];
        ko[d + 16] = (__bf16)(x2 * cp[d + 16] + x1 * sp[d + 16]);
      }
    } else if (q4 == 2) {
      *(bf16x8*)(ko + 32) = *(const bf16x8*)(p + 32);
      *(bf16x8*)(ko + 40) = *(const bf16x8*)(p + 40);
    } else {
      *(bf16x8*)(ko + 48) = *(const bf16x8*)(p + 48);
      *(bf16x8*)(ko + 56) = *(const bf16x8*)(p + 56);
    }
  }
  {
    const __bf16* p = qkv + (size_t)s * 3072 + 2560 + kvh * 64 + q4 * 16;
    *(bf16x8*)&vtile[r][q4 * 16] = *(const bf16x8*)p;
    *(bf16x8*)&vtile[r][q4 * 16 + 8] = *(const bf16x8*)(p + 8);
  }
  __syncthreads();
  {
    int d = t >> 2;
    __bf16* vo = Vt + ((size_t)kvh * 64 + d) * 2048 + st + q4 * 16;
#pragma unroll
    for (int j = 0; j < 16; ++j) vo[j] = vtile[q4 * 16 + j][d];
  }
}

// ---------------------------------------------------------------- flash attention
// QBLK=128 (4 waves x 32 q rows), KVBLK=64, swapped QK^T, in-register P.
__global__ __launch_bounds__(256) void attn_fwd(const __bf16* __restrict__ qkv,
                                                const __bf16* __restrict__ Kr,
                                                const __bf16* __restrict__ Vt,
                                                __bf16* __restrict__ O) {
  const int S = 2048, LDQ = 3072;
  int qt = 15 - blockIdx.x;  // longest first
  int h = blockIdx.y;
  int kvh = h >> 2;
  int t = threadIdx.x;
  int lane = t & 63, w = t >> 6;
  int lmod = lane & 15, ldiv = lane >> 4;

  __shared__ alignas(16) __bf16 Ks[64][72];
  __shared__ alignas(16) __bf16 Vs[64][72];

  int R0 = qt * 128 + w * 32;  // this wave's first q row

  // Q fragments (B-operand): qf[qg][dchunk]
  bf16x8 qf[2][2];
#pragma unroll
  for (int qg = 0; qg < 2; ++qg) {
    const __bf16* qp = qkv + (size_t)(R0 + qg * 16 + lmod) * LDQ + h * 64 + ldiv * 8;
    qf[qg][0] = *(const bf16x8*)qp;
    qf[qg][1] = *(const bf16x8*)(qp + 32);
  }

  f32x4 acc[2][4] = {};
  float m2[2] = {-1e30f, -1e30f};
  float lr[2] = {0.f, 0.f};
  const float cs = 0.125f * LOG2E;

  int nkt = 2 * qt + 2;
  int ktd = (R0 + 31) >> 6;  // this wave's diagonal tile

  // staging: thread t loads K row (t>>2), cols (t&3)*16..+15 ; V row d=(t>>2)
  int srow = t >> 2;
  int scol = (t & 3) * 16;
  const __bf16* kg = Kr + ((size_t)kvh * S + srow) * 64 + scol;
  const __bf16* vg = Vt + ((size_t)kvh * 64 + srow) * S + scol;
  __bf16* ksl = &Ks[srow][scol];
  __bf16* vsl = &Vs[srow][scol];

  bf16x8 kpre0, kpre1, vpre0, vpre1;
  kpre0 = *(const bf16x8*)kg;
  kpre1 = *(const bf16x8*)(kg + 8);
  vpre0 = *(const bf16x8*)vg;
  vpre1 = *(const bf16x8*)(vg + 8);
  *(bf16x8*)ksl = kpre0;
  *(bf16x8*)(ksl + 8) = kpre1;
  *(bf16x8*)vsl = vpre0;
  *(bf16x8*)(vsl + 8) = vpre1;
  __syncthreads();

  int srcA = lmod + ((lane & 16) << 1);  // lmod + 32*(ldiv&1)
  int srcB = srcA + 16;
  bool tsel = (ldiv < 2);

  for (int kt = 0; kt < nkt; ++kt) {
    int ks = kt * 64;
    if (kt + 1 < nkt) {  // prefetch next tile into regs (latency hides under compute)
      const __bf16* kg2 = kg + (size_t)(ks + 64) * 64;
      const __bf16* vg2 = vg + ks + 64;
      kpre0 = *(const bf16x8*)kg2;
      kpre1 = *(const bf16x8*)(kg2 + 8);
      vpre0 = *(const bf16x8*)vg2;
      vpre1 = *(const bf16x8*)(vg2 + 8);
    }
    if (kt <= ktd) {
      // ---- QK^T (swapped): st[qg][t16], lane holds S[k=t16*16+ldiv*4+r][q=lmod]
      f32x4 st[2][4] = {};
      __builtin_amdgcn_s_setprio(1);
#pragma unroll
      for (int t16 = 0; t16 < 4; ++t16) {
        bf16x8 kf0 = *(const bf16x8*)&Ks[t16 * 16 + lmod][ldiv * 8];
        bf16x8 kf1 = *(const bf16x8*)&Ks[t16 * 16 + lmod][32 + ldiv * 8];
        st[0][t16] = MFMA16(kf0, qf[0][0], st[0][t16]);
        st[0][t16] = MFMA16(kf1, qf[0][1], st[0][t16]);
        st[1][t16] = MFMA16(kf0, qf[1][0], st[1][t16]);
        st[1][t16] = MFMA16(kf1, qf[1][1], st[1][t16]);
      }
      __builtin_amdgcn_s_setprio(0);

      if (kt == ktd) {  // diagonal tile: causal mask
#pragma unroll
        for (int qg = 0; qg < 2; ++qg) {
          int qq = R0 + qg * 16 + lmod;
#pragma unroll
          for (int t16 = 0; t16 < 4; ++t16) {
            int kk = ks + t16 * 16 + ldiv * 4;
#pragma unroll
            for (int r = 0; r < 4; ++r)
              st[qg][t16][r] = (kk + r) <= qq ? st[qg][t16][r] : -1e30f;
          }
        }
      }

      // V fragments for PV (shared by both q-groups)
      bf16x8 vf[8];
#pragma unroll
      for (int g = 0; g < 4; ++g) {
        vf[g] = *(const bf16x8*)&Vs[g * 16 + lmod][ldiv * 8];
        vf[4 + g] = *(const bf16x8*)&Vs[g * 16 + lmod][32 + ldiv * 8];
      }

#pragma unroll
      for (int qg = 0; qg < 2; ++qg) {
        // row max (16 in-lane + 2 cross-lane)
        float pm = st[qg][0][0];
#pragma unroll
        for (int t16 = 0; t16 < 4; ++t16)
#pragma unroll
          for (int r = 0; r < 4; ++r) pm = fmaxf(pm, st[qg][t16][r]);
        pm = fmaxf(pm, __shfl_xor(pm, 16));
        pm = fmaxf(pm, __shfl_xor(pm, 32));
        float m2n = pm * cs;

        bool grow = !__all(m2n <= m2[qg] + 8.0f);  // defer-max (T13)
        float al = 1.0f;
        if (grow) {
          al = exp2f(m2[qg] - m2n);
          m2[qg] = m2n;
        }

        // p = exp2(s*cs - m2), in place; row sum
        float rs = 0.f;
#pragma unroll
        for (int t16 = 0; t16 < 4; ++t16)
#pragma unroll
          for (int r = 0; r < 4; ++r) {
            float pv = exp2f(st[qg][t16][r] * cs - m2[qg]);
            st[qg][t16][r] = pv;
            rs += pv;
          }
        rs += __shfl_xor(rs, 16);
        rs += __shfl_xor(rs, 32);
        lr[qg] = lr[qg] * al + rs;

        if (grow) {
          float alq[4];
#pragma unroll
          for (int r = 0; r < 4; ++r) alq[r] = __shfl(al, ldiv * 4 + r);
#pragma unroll
          for (int g = 0; g < 4; ++g)
#pragma unroll
            for (int r = 0; r < 4; ++r) acc[qg][g][r] *= alq[r];
        }

        // pack P to bf16 pairs: b[t16][pair]
        uint32_t b0 = pk2(st[qg][0][0], st[qg][0][1]);
        uint32_t b1 = pk2(st[qg][0][2], st[qg][0][3]);
        uint32_t b2 = pk2(st[qg][1][0], st[qg][1][1]);
        uint32_t b3 = pk2(st[qg][1][2], st[qg][1][3]);
        uint32_t b4 = pk2(st[qg][2][0], st[qg][2][1]);
        uint32_t b5 = pk2(st[qg][2][2], st[qg][2][3]);
        uint32_t b6 = pk2(st[qg][3][0], st[qg][3][1]);
        uint32_t b7 = pk2(st[qg][3][2], st[qg][3][3]);

        // redistribute to PV A-fragment layout (within-wave, no LDS)
        uint32_t x, y;
        u32x4 av0, av1;
        x = (uint32_t)__shfl((int)b0, srcA); y = (uint32_t)__shfl((int)b2, srcA); av0[0] = tsel ? x : y;
        x = (uint32_t)__shfl((int)b1, srcA); y = (uint32_t)__shfl((int)b3, srcA); av0[1] = tsel ? x : y;
        x = (uint32_t)__shfl((int)b0, srcB); y = (uint32_t)__shfl((int)b2, srcB); av0[2] = tsel ? x : y;
        x = (uint32_t)__shfl((int)b1, srcB); y = (uint32_t)__shfl((int)b3, srcB); av0[3] = tsel ? x : y;
        x = (uint32_t)__shfl((int)b4, srcA); y = (uint32_t)__shfl((int)b6, srcA); av1[0] = tsel ? x : y;
        x = (uint32_t)__shfl((int)b5, srcA); y = (uint32_t)__shfl((int)b7, srcA); av1[1] = tsel ? x : y;
        x = (uint32_t)__shfl((int)b4, srcB); y = (uint32_t)__shfl((int)b6, srcB); av1[2] = tsel ? x : y;
        x = (uint32_t)__shfl((int)b5, srcB); y = (uint32_t)__shfl((int)b7, srcB); av1[3] = tsel ? x : y;
        bf16x8 pa0 = __builtin_bit_cast(bf16x8, av0);
        bf16x8 pa1 = __builtin_bit_cast(bf16x8, av1);

        __builtin_amdgcn_s_setprio(1);
#pragma unroll
        for (int g = 0; g < 4; ++g) {
          acc[qg][g] = MFMA16(pa0, vf[g], acc[qg][g]);
          acc[qg][g] = MFMA16(pa1, vf[4 + g], acc[qg][g]);
        }
        __builtin_amdgcn_s_setprio(0);
      }
    }
    __syncthreads();
    if (kt + 1 < nkt) {
      *(bf16x8*)ksl = kpre0;
      *(bf16x8*)(ksl + 8) = kpre1;
      *(bf16x8*)vsl = vpre0;
      *(bf16x8*)(vsl + 8) = vpre1;
    }
    __syncthreads();
  }

  // epilogue: O[q][h*64+d] = acc / l
#pragma unroll
  for (int qg = 0; qg < 2; ++qg) {
    float linv[4];
#pragma unroll
    for (int r = 0; r < 4; ++r) {
      float lq = __shfl(lr[qg], ldiv * 4 + r);
      linv[r] = 1.0f / lq;
    }
#pragma unroll
    for (int g = 0; g < 4; ++g)
#pragma unroll
      for (int r = 0; r < 4; ++r)
        O[(size_t)(R0 + qg * 16 + ldiv * 4 + r) * 2048 + h * 64 + g * 16 + lmod] =
            (__bf16)(acc[qg][g][r] * linv[r]);
  }
}

// ---------------------------------------------------------------- launch
extern "C" void kernel_launch(void* const* d_in, const int* in_sizes, int n_in,
                              void* d_out, int out_size, void* d_ws, size_t ws_size,
                              hipStream_t stream) {
  const float* x = (const float*)d_in[0];
  const float* cosb = (const float*)d_in[1];
  const float* sinb = (const float*)d_in[2];
  const float* wqkv = (const float*)d_in[3];
  const float* wo = (const float*)d_in[4];
  float* out = (float*)d_out;

  char* ws = (char*)d_ws;
  __bf16* xb    = (__bf16*)(ws + 0);
  __bf16* wqkvT = (__bf16*)(ws + 8388608);
  __bf16* woT   = (__bf16*)(ws + 20971520);
  __bf16* qkvb  = (__bf16*)(ws + 29360128);
  __bf16* Krb   = (__bf16*)(ws + 41943040);
  __bf16* Vtb   = (__bf16*)(ws + 44040192);
  __bf16* attnb = (__bf16*)(ws + 46137344);

  cvt_f32_bf16<<<4096, 256, 0, stream>>>(x, xb);
  transpose_f32_bf16<<<dim3(48, 32), 256, 0, stream>>>(wqkv, wqkvT, 2048, 3072);
  transpose_f32_bf16<<<dim3(32, 32), 256, 0, stream>>>(wo, woT, 2048, 2048);
  gemm_bt<__bf16><<<dim3(24, 16), 256, 0, stream>>>(xb, wqkvT, qkvb, 2048, 3072, 2048);
  rope_restruct<<<dim3(32, 8), 256, 0, stream>>>(qkvb, cosb, sinb, Krb, Vtb);
  attn_fwd<<<dim3(16, 32), 256, 0, stream>>>(qkvb, Krb, Vtb, attnb);
  gemm_bt<float><<<dim3(16, 16), 256, 0, stream>>>(attnb, woT, out, 2048, 2048, 2048);
}

// Round 3
// 197.094 us; speedup vs baseline: 1.5466x; 1.1022x over previous
//
#include <hip/hip_runtime.h>
#include <hip/hip_bf16.h>
#include <stdint.h>

typedef float f32x4 __attribute__((ext_vector_type(4)));
typedef float f32x4v __attribute__((ext_vector_type(4)));
typedef __bf16 bf16x8 __attribute__((ext_vector_type(8)));
typedef __bf16 bf16x4 __attribute__((ext_vector_type(4)));
typedef __bf16 bf16x2 __attribute__((ext_vector_type(2)));
typedef unsigned int u32x4 __attribute__((ext_vector_type(4)));

#define LOG2E 1.44269504088896340736f
#define MFMA16(a, b, c) __builtin_amdgcn_mfma_f32_16x16x32_bf16((a), (b), (c), 0, 0, 0)

static __device__ __forceinline__ void gload_lds16(const void* g, void* l) {
  __builtin_amdgcn_global_load_lds(
      (const __attribute__((address_space(1))) unsigned int*)g,
      (__attribute__((address_space(3))) unsigned int*)l, 16, 0, 0);
}

static __device__ __forceinline__ uint32_t pk2(float lo, float hi) {
  bf16x2 v;
  v[0] = (__bf16)lo;
  v[1] = (__bf16)hi;
  return __builtin_bit_cast(uint32_t, v);
}

// ---------------------------------------------------------------- converts
__global__ __launch_bounds__(256) void cvt_f32_bf16(const float* __restrict__ in,
                                                    __bf16* __restrict__ out) {
  int i = blockIdx.x * 256 + threadIdx.x;
  f32x4v v = *(const f32x4v*)(in + (size_t)i * 4);
  bf16x4 o;
  o[0] = (__bf16)v[0]; o[1] = (__bf16)v[1]; o[2] = (__bf16)v[2]; o[3] = (__bf16)v[3];
  *(bf16x4*)(out + (size_t)i * 4) = o;
}

// in [R][C] f32 -> out [C][R] bf16, 64x64 tiles
__global__ __launch_bounds__(256) void transpose_f32_bf16(const float* __restrict__ in,
                                                          __bf16* __restrict__ out,
                                                          int R, int C) {
  __shared__ float tile[64][65];
  int tr = blockIdx.y * 64, tc = blockIdx.x * 64;
  int t = threadIdx.x;
  int r0 = t >> 4;
  int c4 = (t & 15) * 4;
#pragma unroll
  for (int i = 0; i < 4; ++i) {
    int r = r0 + i * 16;
    f32x4v v = *(const f32x4v*)(in + (size_t)(tr + r) * C + tc + c4);
    tile[r][c4 + 0] = v[0]; tile[r][c4 + 1] = v[1];
    tile[r][c4 + 2] = v[2]; tile[r][c4 + 3] = v[3];
  }
  __syncthreads();
#pragma unroll
  for (int i = 0; i < 4; ++i) {
    int r = r0 + i * 16;
    __bf16* o = out + (size_t)(tc + r) * R + tr + c4;
    bf16x4 ov;
    ov[0] = (__bf16)tile[c4 + 0][r]; ov[1] = (__bf16)tile[c4 + 1][r];
    ov[2] = (__bf16)tile[c4 + 2][r]; ov[3] = (__bf16)tile[c4 + 3][r];
    *(bf16x4*)o = ov;
  }
}

// ---------------------------------------------------------------- GEMM: 8-wave, dbuf, 1 barrier/iter
// C[M][N] = A[M][K] * BT[N][K]^T. 128x128 tile, BK=32, wave w owns 32x64 quadrant.
template <typename OutT>
__global__ __launch_bounds__(512) void gemm8(const __bf16* __restrict__ A,
                                             const __bf16* __restrict__ BT,
                                             OutT* __restrict__ C,
                                             int M, int N, int K) {
  __shared__ alignas(16) __bf16 As[2][128 * 32];
  __shared__ alignas(16) __bf16 Bs[2][128 * 32];
  int bn = blockIdx.x, bm = blockIdx.y;
  int t = threadIdx.x;
  int lane = t & 63, w = t >> 6;  // 8 waves
  int lmod = lane & 15, ldiv = lane >> 4;
  int wr = w >> 1, wc = w & 1;

  f32x4 acc[2][4] = {};

  // staging: wave w loads rows w*16..w*16+15 (1KB chunk) of As and Bs
  int srow = lane >> 2;
  int scol = (lane & 3) * 8;
  const __bf16* ga = A + (size_t)(bm * 128 + w * 16 + srow) * K + scol;
  const __bf16* gb = BT + (size_t)(bn * 128 + w * 16 + srow) * K + scol;

  gload_lds16(ga, &As[0][w * 512]);
  gload_lds16(gb, &Bs[0][w * 512]);

  int cur = 0;
  for (int k0 = 0; k0 < K; k0 += 32) {
    __syncthreads();  // drains own vmcnt: cur-tile loads (issued one full iter ago)
    if (k0 + 32 < K) {
      gload_lds16(ga + k0 + 32, &As[cur ^ 1][w * 512]);
      gload_lds16(gb + k0 + 32, &Bs[cur ^ 1][w * 512]);
    }
    bf16x8 af[2], bfr[4];
#pragma unroll
    for (int i = 0; i < 2; ++i)
      af[i] = *(const bf16x8*)(&As[cur][(wr * 32 + i * 16 + lmod) * 32 + ldiv * 8]);
#pragma unroll
    for (int j = 0; j < 4; ++j)
      bfr[j] = *(const bf16x8*)(&Bs[cur][(wc * 64 + j * 16 + lmod) * 32 + ldiv * 8]);
    __builtin_amdgcn_s_setprio(1);
#pragma unroll
    for (int i = 0; i < 2; ++i)
#pragma unroll
      for (int j = 0; j < 4; ++j)
        acc[i][j] = MFMA16(af[i], bfr[j], acc[i][j]);
    __builtin_amdgcn_s_setprio(0);
    cur ^= 1;
  }

#pragma unroll
  for (int i = 0; i < 2; ++i) {
    int row0 = bm * 128 + wr * 32 + i * 16 + ldiv * 4;
#pragma unroll
    for (int j = 0; j < 4; ++j) {
      int col = bn * 128 + wc * 64 + j * 16 + lmod;
#pragma unroll
      for (int r = 0; r < 4; ++r)
        C[(size_t)(row0 + r) * N + col] = (OutT)acc[i][j][r];
    }
  }
}

// ---------------------------------------------------------------- RoPE + restructure
__global__ __launch_bounds__(256) void rope_restruct(__bf16* __restrict__ qkv,
                                                     const float* __restrict__ cosb,
                                                     const float* __restrict__ sinb,
                                                     __bf16* __restrict__ Kr,
                                                     __bf16* __restrict__ Vt) {
  int st = blockIdx.x * 64;
  int kvh = blockIdx.y;
  int t = threadIdx.x;
  __shared__ alignas(16) __bf16 vtile[64][72];

  int r = t >> 2;
  int q4 = t & 3;
  int s = st + r;
  const float* cp = cosb + (size_t)s * 32;
  const float* sp = sinb + (size_t)s * 32;

  {
    __bf16* p = qkv + (size_t)s * 3072 + (kvh * 4 + q4) * 64;
#pragma unroll
    for (int d = 0; d < 16; ++d) {
      float x1 = (float)p[d], x2 = (float)p[d + 16];
      float o1 = x1 * cp[d] - x2 * sp[d];
      float o2 = x2 * cp[d + 16] + x1 * sp[d + 16];
      p[d] = (__bf16)o1;
      p[d + 16] = (__bf16)o2;
    }
  }
  {
    const __bf16* p = qkv + (size_t)s * 3072 + 2048 + kvh * 64;
    __bf16* ko = Kr + ((size_t)kvh * 2048 + s) * 64;
    if (q4 == 0) {
#pragma unroll
      for (int d = 0; d < 16; ++d) {
        float x1 = (float)p[d], x2 = (float)p[d + 16];
        ko[d] = (__bf16)(x1 * cp[d] - x2 * sp[d]);
      }
    } else if (q4 == 1) {
#pragma unroll
      for (int d = 0; d < 16; ++d) {
        float x1 = (float)p[d], x2 = (float)p[d + 16];
        ko[d + 16] = (__bf16)(x2 * cp[d + 16] + x1 * sp[d + 16]);
      }
    } else if (q4 == 2) {
      *(bf16x8*)(ko + 32) = *(const bf16x8*)(p + 32);
      *(bf16x8*)(ko + 40) = *(const bf16x8*)(p + 40);
    } else {
      *(bf16x8*)(ko + 48) = *(const bf16x8*)(p + 48);
      *(bf16x8*)(ko + 56) = *(const bf16x8*)(p + 56);
    }
  }
  {
    const __bf16* p = qkv + (size_t)s * 3072 + 2560 + kvh * 64 + q4 * 16;
    *(bf16x8*)&vtile[r][q4 * 16] = *(const bf16x8*)p;
    *(bf16x8*)&vtile[r][q4 * 16 + 8] = *(const bf16x8*)(p + 8);
  }
  __syncthreads();
  {
    int d = t >> 2;
    __bf16* vo = Vt + ((size_t)kvh * 64 + d) * 2048 + st + q4 * 16;
#pragma unroll
    for (int j = 0; j < 16; ++j) vo[j] = vtile[q4 * 16 + j][d];
  }
}

// ---------------------------------------------------------------- flash attention v3
// QBLK=64 (2 waves x 32 q rows), KVBLK=64, 2048 blocks, swapped QK^T, in-reg P,
// gload_lds staging w/ XOR-swizzled source+reads, double-buffer, 1 barrier/tile.
__global__ __launch_bounds__(128) void attn_fwd(const __bf16* __restrict__ qkv,
                                                const __bf16* __restrict__ Kr,
                                                const __bf16* __restrict__ Vt,
                                                __bf16* __restrict__ O) {
  const int S = 2048, LDQ = 3072;
  int qt = 31 - blockIdx.x;  // longest first
  int h = blockIdx.y;
  int kvh = h >> 2;
  int t = threadIdx.x;
  int lane = t & 63, w = t >> 6;  // 2 waves
  int lmod = lane & 15, ldiv = lane >> 4;

  __shared__ alignas(16) __bf16 KV[2][2][64 * 64];  // [buf][K/V][row*64+col], 32KB

  int R0 = qt * 64 + w * 32;

  bf16x8 qf[2][2];
#pragma unroll
  for (int qg = 0; qg < 2; ++qg) {
    const __bf16* qp = qkv + (size_t)(R0 + qg * 16 + lmod) * LDQ + h * 64 + ldiv * 8;
    qf[qg][0] = *(const bf16x8*)qp;
    qf[qg][1] = *(const bf16x8*)(qp + 32);
  }

  f32x4 acc[2][4] = {};
  float m2[2] = {-1e30f, -1e30f};
  float lr[2] = {0.f, 0.f};
  const float cs = 0.125f * LOG2E;
  int nkt = qt + 1;

  // staging: wave w stages 1KB chunks c1kb = w*4+c (c=0..3) of K and V tiles.
  // LDS linear [row][64]; global source pre-swizzled: inrow16 ^= (row&7).
  const __bf16* Kg = Kr + (size_t)kvh * S * 64;
  const __bf16* Vg = Vt + (size_t)kvh * 64 * S;
  int srow8 = lane >> 3;            // row-within-8 of this lane's chunk
  int schk = (lane & 7) ^ srow8;    // swizzled in-row 16B-chunk index

#define STAGE(buf, ks)                                                          \
  {                                                                             \
    __bf16* kb = &KV[buf][0][0];                                                \
    __bf16* vb = &KV[buf][1][0];                                                \
    _Pragma("unroll") for (int c = 0; c < 4; ++c) {                             \
      int c1kb = w * 4 + c;                                                     \
      int rr = c1kb * 8 + srow8;                                                \
      gload_lds16(Kg + (size_t)((ks) + rr) * 64 + schk * 8, kb + c1kb * 512);   \
      gload_lds16(Vg + (size_t)rr * S + (ks) + schk * 8, vb + c1kb * 512);      \
    }                                                                           \
  }

  STAGE(0, 0);

  int srcA = lmod + ((lane & 16) << 1);
  int srcB = srcA + 16;
  bool tsel = (ldiv < 2);
  int r7 = lmod & 7;
  int ca = ldiv ^ r7;        // swizzled chunk, k-slots 0..31 half
  int cb = (4 + ldiv) ^ r7;  // k-slots 32..63 half

  int cur = 0;
  for (int kt = 0; kt < nkt; ++kt) {
    int ks = kt * 64;
    __syncthreads();  // drains own gload vmcnt; cur tile visible for all waves
    if (kt + 1 < nkt) STAGE(cur ^ 1, ks + 64);
    const __bf16* Ksb = &KV[cur][0][0];
    const __bf16* Vsb = &KV[cur][1][0];

    // ---- QK^T (swapped): lane holds S[k=t16*16+ldiv*4+r][q=lmod]
    f32x4 st[2][4] = {};
    __builtin_amdgcn_s_setprio(1);
#pragma unroll
    for (int t16 = 0; t16 < 4; ++t16) {
      int row = t16 * 16 + lmod;
      bf16x8 kf0 = *(const bf16x8*)(Ksb + row * 64 + ca * 8);
      bf16x8 kf1 = *(const bf16x8*)(Ksb + row * 64 + cb * 8);
      st[0][t16] = MFMA16(kf0, qf[0][0], st[0][t16]);
      st[0][t16] = MFMA16(kf1, qf[0][1], st[0][t16]);
      st[1][t16] = MFMA16(kf0, qf[1][0], st[1][t16]);
      st[1][t16] = MFMA16(kf1, qf[1][1], st[1][t16]);
    }
    __builtin_amdgcn_s_setprio(0);

    if (kt == nkt - 1) {  // diagonal tile: causal mask
#pragma unroll
      for (int qg = 0; qg < 2; ++qg) {
        int qq = R0 + qg * 16 + lmod;
#pragma unroll
        for (int t16 = 0; t16 < 4; ++t16) {
          int kk = ks + t16 * 16 + ldiv * 4;
#pragma unroll
          for (int r = 0; r < 4; ++r)
            st[qg][t16][r] = (kk + r) <= qq ? st[qg][t16][r] : -1e30f;
        }
      }
    }

    // V fragments (shared by both q-groups)
    bf16x8 vf[8];
#pragma unroll
    for (int g = 0; g < 4; ++g) {
      int row = g * 16 + lmod;
      vf[g] = *(const bf16x8*)(Vsb + row * 64 + ca * 8);
      vf[4 + g] = *(const bf16x8*)(Vsb + row * 64 + cb * 8);
    }

#pragma unroll
    for (int qg = 0; qg < 2; ++qg) {
      float pm = st[qg][0][0];
#pragma unroll
      for (int t16 = 0; t16 < 4; ++t16)
#pragma unroll
        for (int r = 0; r < 4; ++r) pm = fmaxf(pm, st[qg][t16][r]);
      pm = fmaxf(pm, __shfl_xor(pm, 16));
      pm = fmaxf(pm, __shfl_xor(pm, 32));
      float m2n = pm * cs;

      bool grow = !__all(m2n <= m2[qg] + 8.0f);  // defer-max
      float al = 1.0f;
      if (grow) {
        al = exp2f(m2[qg] - m2n);
        m2[qg] = m2n;
      }

      float rs = 0.f;
#pragma unroll
      for (int t16 = 0; t16 < 4; ++t16)
#pragma unroll
        for (int r = 0; r < 4; ++r) {
          float pv = exp2f(st[qg][t16][r] * cs - m2[qg]);
          st[qg][t16][r] = pv;
          rs += pv;
        }
      rs += __shfl_xor(rs, 16);
      rs += __shfl_xor(rs, 32);
      lr[qg] = lr[qg] * al + rs;

      if (grow) {
        float alq[4];
#pragma unroll
        for (int r = 0; r < 4; ++r) alq[r] = __shfl(al, ldiv * 4 + r);
#pragma unroll
        for (int g = 0; g < 4; ++g)
#pragma unroll
          for (int r = 0; r < 4; ++r) acc[qg][g][r] *= alq[r];
      }

      uint32_t b0 = pk2(st[qg][0][0], st[qg][0][1]);
      uint32_t b1 = pk2(st[qg][0][2], st[qg][0][3]);
      uint32_t b2 = pk2(st[qg][1][0], st[qg][1][1]);
      uint32_t b3 = pk2(st[qg][1][2], st[qg][1][3]);
      uint32_t b4 = pk2(st[qg][2][0], st[qg][2][1]);
      uint32_t b5 = pk2(st[qg][2][2], st[qg][2][3]);
      uint32_t b6 = pk2(st[qg][3][0], st[qg][3][1]);
      uint32_t b7 = pk2(st[qg][3][2], st[qg][3][3]);

      uint32_t x, y;
      u32x4 av0, av1;
      x = (uint32_t)__shfl((int)b0, srcA); y = (uint32_t)__shfl((int)b2, srcA); av0[0] = tsel ? x : y;
      x = (uint32_t)__shfl((int)b1, srcA); y = (uint32_t)__shfl((int)b3, srcA); av0[1] = tsel ? x : y;
      x = (uint32_t)__shfl((int)b0, srcB); y = (uint32_t)__shfl((int)b2, srcB); av0[2] = tsel ? x : y;
      x = (uint32_t)__shfl((int)b1, srcB); y = (uint32_t)__shfl((int)b3, srcB); av0[3] = tsel ? x : y;
      x = (uint32_t)__shfl((int)b4, srcA); y = (uint32_t)__shfl((int)b6, srcA); av1[0] = tsel ? x : y;
      x = (uint32_t)__shfl((int)b5, srcA); y = (uint32_t)__shfl((int)b7, srcA); av1[1] = tsel ? x : y;
      x = (uint32_t)__shfl((int)b4, srcB); y = (uint32_t)__shfl((int)b6, srcB); av1[2] = tsel ? x : y;
      x = (uint32_t)__shfl((int)b5, srcB); y = (uint32_t)__shfl((int)b7, srcB); av1[3] = tsel ? x : y;
      bf16x8 pa0 = __builtin_bit_cast(bf16x8, av0);
      bf16x8 pa1 = __builtin_bit_cast(bf16x8, av1);

      __builtin_amdgcn_s_setprio(1);
#pragma unroll
      for (int g = 0; g < 4; ++g) {
        acc[qg][g] = MFMA16(pa0, vf[g], acc[qg][g]);
        acc[qg][g] = MFMA16(pa1, vf[4 + g], acc[qg][g]);
      }
      __builtin_amdgcn_s_setprio(0);
    }
    cur ^= 1;
  }

#pragma unroll
  for (int qg = 0; qg < 2; ++qg) {
    float linv[4];
#pragma unroll
    for (int r = 0; r < 4; ++r) {
      float lq = __shfl(lr[qg], ldiv * 4 + r);
      linv[r] = 1.0f / lq;
    }
#pragma unroll
    for (int g = 0; g < 4; ++g)
#pragma unroll
      for (int r = 0; r < 4; ++r)
        O[(size_t)(R0 + qg * 16 + ldiv * 4 + r) * 2048 + h * 64 + g * 16 + lmod] =
            (__bf16)(acc[qg][g][r] * linv[r]);
  }
}

// ---------------------------------------------------------------- launch
extern "C" void kernel_launch(void* const* d_in, const int* in_sizes, int n_in,
                              void* d_out, int out_size, void* d_ws, size_t ws_size,
                              hipStream_t stream) {
  const float* x = (const float*)d_in[0];
  const float* cosb = (const float*)d_in[1];
  const float* sinb = (const float*)d_in[2];
  const float* wqkv = (const float*)d_in[3];
  const float* wo = (const float*)d_in[4];
  float* out = (float*)d_out;

  char* ws = (char*)d_ws;
  __bf16* xb    = (__bf16*)(ws + 0);
  __bf16* wqkvT = (__bf16*)(ws + 8388608);
  __bf16* woT   = (__bf16*)(ws + 20971520);
  __bf16* qkvb  = (__bf16*)(ws + 29360128);
  __bf16* Krb   = (__bf16*)(ws + 41943040);
  __bf16* Vtb   = (__bf16*)(ws + 44040192);
  __bf16* attnb = (__bf16*)(ws + 46137344);

  cvt_f32_bf16<<<4096, 256, 0, stream>>>(x, xb);
  transpose_f32_bf16<<<dim3(48, 32), 256, 0, stream>>>(wqkv, wqkvT, 2048, 3072);
  transpose_f32_bf16<<<dim3(32, 32), 256, 0, stream>>>(wo, woT, 2048, 2048);
  gemm8<__bf16><<<dim3(24, 16), 512, 0, stream>>>(xb, wqkvT, qkvb, 2048, 3072, 2048);
  rope_restruct<<<dim3(32, 8), 256, 0, stream>>>(qkvb, cosb, sinb, Krb, Vtb);
  attn_fwd<<<dim3(32, 32), 128, 0, stream>>>(qkvb, Krb, Vtb, attnb);
  gemm8<float><<<dim3(16, 16), 512, 0, stream>>>(attnb, woT, out, 2048, 2048, 2048);
}

// Round 4
// 195.900 us; speedup vs baseline: 1.5560x; 1.0061x over previous
//
#include <hip/hip_runtime.h>
#include <hip/hip_bf16.h>
#include <stdint.h>

typedef float f32x4 __attribute__((ext_vector_type(4)));
typedef float f32x4v __attribute__((ext_vector_type(4)));
typedef __bf16 bf16x8 __attribute__((ext_vector_type(8)));
typedef __bf16 bf16x4 __attribute__((ext_vector_type(4)));
typedef __bf16 bf16x2 __attribute__((ext_vector_type(2)));
typedef unsigned int u32x4 __attribute__((ext_vector_type(4)));

#define LOG2E 1.44269504088896340736f
#define MFMA16(a, b, c) __builtin_amdgcn_mfma_f32_16x16x32_bf16((a), (b), (c), 0, 0, 0)

static __device__ __forceinline__ void gload_lds16(const void* g, void* l) {
  __builtin_amdgcn_global_load_lds(
      (const __attribute__((address_space(1))) unsigned int*)g,
      (__attribute__((address_space(3))) unsigned int*)l, 16, 0, 0);
}

static __device__ __forceinline__ uint32_t pk2(float lo, float hi) {
  bf16x2 v;
  v[0] = (__bf16)lo;
  v[1] = (__bf16)hi;
  return __builtin_bit_cast(uint32_t, v);
}

// ---------------------------------------------------------------- converts
__global__ __launch_bounds__(256) void cvt_f32_bf16(const float* __restrict__ in,
                                                    __bf16* __restrict__ out) {
  int i = blockIdx.x * 256 + threadIdx.x;
  f32x4v v = *(const f32x4v*)(in + (size_t)i * 4);
  bf16x4 o;
  o[0] = (__bf16)v[0]; o[1] = (__bf16)v[1]; o[2] = (__bf16)v[2]; o[3] = (__bf16)v[3];
  *(bf16x4*)(out + (size_t)i * 4) = o;
}

// in [R][C] f32 -> out [C][R] bf16, 64x64 tiles
__global__ __launch_bounds__(256) void transpose_f32_bf16(const float* __restrict__ in,
                                                          __bf16* __restrict__ out,
                                                          int R, int C) {
  __shared__ float tile[64][65];
  int tr = blockIdx.y * 64, tc = blockIdx.x * 64;
  int t = threadIdx.x;
  int r0 = t >> 4;
  int c4 = (t & 15) * 4;
#pragma unroll
  for (int i = 0; i < 4; ++i) {
    int r = r0 + i * 16;
    f32x4v v = *(const f32x4v*)(in + (size_t)(tr + r) * C + tc + c4);
    tile[r][c4 + 0] = v[0]; tile[r][c4 + 1] = v[1];
    tile[r][c4 + 2] = v[2]; tile[r][c4 + 3] = v[3];
  }
  __syncthreads();
#pragma unroll
  for (int i = 0; i < 4; ++i) {
    int r = r0 + i * 16;
    __bf16* o = out + (size_t)(tc + r) * R + tr + c4;
    bf16x4 ov;
    ov[0] = (__bf16)tile[c4 + 0][r]; ov[1] = (__bf16)tile[c4 + 1][r];
    ov[2] = (__bf16)tile[c4 + 2][r]; ov[3] = (__bf16)tile[c4 + 3][r];
    *(bf16x4*)o = ov;
  }
}

// ---------------------------------------------------------------- GEMM: 8-wave, 3-buf, counted vmcnt
// C[M][N] = A[M][K] * BT[N][K]^T. 128x128 tile, BK=32, wave w owns 32x64 quadrant.
// Pipeline: STAGE(t+2); vmcnt(4); s_barrier; ds_read+MFMA(t); s_barrier.
template <typename OutT>
__global__ __launch_bounds__(512) void gemm8(const __bf16* __restrict__ A,
                                             const __bf16* __restrict__ BT,
                                             OutT* __restrict__ C,
                                             int M, int N, int K) {
  __shared__ alignas(16) __bf16 As[3][4096];
  __shared__ alignas(16) __bf16 Bs[3][4096];
  int bn = blockIdx.x, bm = blockIdx.y;
  int t = threadIdx.x;
  int lane = t & 63, w = t >> 6;  // 8 waves
  int lmod = lane & 15, ldiv = lane >> 4;
  int wr = w >> 1, wc = w & 1;

  f32x4 acc[2][4] = {};

  int srow = lane >> 2;
  int scol = (lane & 3) * 8;
  const __bf16* ga = A + (size_t)(bm * 128 + w * 16 + srow) * K + scol;
  const __bf16* gb = BT + (size_t)(bn * 128 + w * 16 + srow) * K + scol;

#define GSTAGE(b, tt)                                  \
  {                                                    \
    gload_lds16(ga + (tt) * 32, &As[b][w * 512]);      \
    gload_lds16(gb + (tt) * 32, &Bs[b][w * 512]);      \
  }

  int NT = K >> 5;
  GSTAGE(0, 0);
  if (NT > 1) GSTAGE(1, 1);

  int bc = 0, bnx = 2;
  for (int tt = 0; tt < NT; ++tt) {
    if (tt + 2 < NT) {
      GSTAGE(bnx, tt + 2);
      asm volatile("s_waitcnt vmcnt(4)" ::: "memory");
    } else if (tt + 1 < NT) {
      asm volatile("s_waitcnt vmcnt(2)" ::: "memory");
    } else {
      asm volatile("s_waitcnt vmcnt(0)" ::: "memory");
    }
    __builtin_amdgcn_s_barrier();
    __builtin_amdgcn_sched_barrier(0);
    bf16x8 af[2], bfr[4];
#pragma unroll
    for (int i = 0; i < 2; ++i)
      af[i] = *(const bf16x8*)(&As[bc][(wr * 32 + i * 16 + lmod) * 32 + ldiv * 8]);
#pragma unroll
    for (int j = 0; j < 4; ++j)
      bfr[j] = *(const bf16x8*)(&Bs[bc][(wc * 64 + j * 16 + lmod) * 32 + ldiv * 8]);
    __builtin_amdgcn_s_setprio(1);
#pragma unroll
    for (int i = 0; i < 2; ++i)
#pragma unroll
      for (int j = 0; j < 4; ++j)
        acc[i][j] = MFMA16(af[i], bfr[j], acc[i][j]);
    __builtin_amdgcn_s_setprio(0);
    __builtin_amdgcn_sched_barrier(0);
    __builtin_amdgcn_s_barrier();
    bc = (bc == 2) ? 0 : bc + 1;
    bnx = (bnx == 2) ? 0 : bnx + 1;
  }

#pragma unroll
  for (int i = 0; i < 2; ++i) {
    int row0 = bm * 128 + wr * 32 + i * 16 + ldiv * 4;
#pragma unroll
    for (int j = 0; j < 4; ++j) {
      int col = bn * 128 + wc * 64 + j * 16 + lmod;
#pragma unroll
      for (int r = 0; r < 4; ++r)
        C[(size_t)(row0 + r) * N + col] = (OutT)acc[i][j][r];
    }
  }
}

// ---------------------------------------------------------------- RoPE + restructure
__global__ __launch_bounds__(256) void rope_restruct(__bf16* __restrict__ qkv,
                                                     const float* __restrict__ cosb,
                                                     const float* __restrict__ sinb,
                                                     __bf16* __restrict__ Kr,
                                                     __bf16* __restrict__ Vt) {
  int st = blockIdx.x * 64;
  int kvh = blockIdx.y;
  int t = threadIdx.x;
  __shared__ alignas(16) __bf16 vtile[64][72];

  int r = t >> 2;
  int q4 = t & 3;
  int s = st + r;
  const float* cp = cosb + (size_t)s * 32;
  const float* sp = sinb + (size_t)s * 32;

  {
    __bf16* p = qkv + (size_t)s * 3072 + (kvh * 4 + q4) * 64;
#pragma unroll
    for (int d = 0; d < 16; ++d) {
      float x1 = (float)p[d], x2 = (float)p[d + 16];
      float o1 = x1 * cp[d] - x2 * sp[d];
      float o2 = x2 * cp[d + 16] + x1 * sp[d + 16];
      p[d] = (__bf16)o1;
      p[d + 16] = (__bf16)o2;
    }
  }
  {
    const __bf16* p = qkv + (size_t)s * 3072 + 2048 + kvh * 64;
    __bf16* ko = Kr + ((size_t)kvh * 2048 + s) * 64;
    if (q4 == 0) {
#pragma unroll
      for (int d = 0; d < 16; ++d) {
        float x1 = (float)p[d], x2 = (float)p[d + 16];
        ko[d] = (__bf16)(x1 * cp[d] - x2 * sp[d]);
      }
    } else if (q4 == 1) {
#pragma unroll
      for (int d = 0; d < 16; ++d) {
        float x1 = (float)p[d], x2 = (float)p[d + 16];
        ko[d + 16] = (__bf16)(x2 * cp[d + 16] + x1 * sp[d + 16]);
      }
    } else if (q4 == 2) {
      *(bf16x8*)(ko + 32) = *(const bf16x8*)(p + 32);
      *(bf16x8*)(ko + 40) = *(const bf16x8*)(p + 40);
    } else {
      *(bf16x8*)(ko + 48) = *(const bf16x8*)(p + 48);
      *(bf16x8*)(ko + 56) = *(const bf16x8*)(p + 56);
    }
  }
  {
    const __bf16* p = qkv + (size_t)s * 3072 + 2560 + kvh * 64 + q4 * 16;
    *(bf16x8*)&vtile[r][q4 * 16] = *(const bf16x8*)p;
    *(bf16x8*)&vtile[r][q4 * 16 + 8] = *(const bf16x8*)(p + 8);
  }
  __syncthreads();
  {
    int d = t >> 2;
    __bf16* vo = Vt + ((size_t)kvh * 64 + d) * 2048 + st + q4 * 16;
#pragma unroll
    for (int j = 0; j < 16; ++j) vo[j] = vtile[q4 * 16 + j][d];
  }
}

// ---------------------------------------------------------------- flash attention v4
// QBLK=64, 4 waves x 16 q rows, KVBLK=64 dbuf, swapped QK^T, in-reg P,
// gload_lds + XOR-swizzled source+reads, balanced qt pairing.
__global__ __launch_bounds__(256) void attn_fwd(const __bf16* __restrict__ qkv,
                                                const __bf16* __restrict__ Kr,
                                                const __bf16* __restrict__ Vt,
                                                __bf16* __restrict__ O) {
  const int S = 2048, LDQ = 3072;
  int i = blockIdx.x;
  int qt = (i & 1) ? (i >> 1) : (31 - (i >> 1));  // pairs sum to 31 tile-units
  int h = blockIdx.y;
  int kvh = h >> 2;
  int t = threadIdx.x;
  int lane = t & 63, w = t >> 6;  // 4 waves
  int lmod = lane & 15, ldiv = lane >> 4;

  __shared__ alignas(16) __bf16 KV[2][2][4096];  // [buf][K/V][row*64+col], 32KB

  int R0 = qt * 64 + w * 16;  // this wave's 16 q rows

  const __bf16* qp = qkv + (size_t)(R0 + lmod) * LDQ + h * 64 + ldiv * 8;
  bf16x8 qf0 = *(const bf16x8*)qp;
  bf16x8 qf1 = *(const bf16x8*)(qp + 32);

  f32x4 acc[4] = {};
  float m2 = -1e30f;
  float lr = 0.f;
  const float cs = 0.125f * LOG2E;
  int nkt = qt + 1;

  // staging: wave w stages 1KB chunks c1kb = w*2+c (c=0..1) of K and V tiles.
  const __bf16* Kg = Kr + (size_t)kvh * S * 64;
  const __bf16* Vg = Vt + (size_t)kvh * 64 * S;
  int srow8 = lane >> 3;          // row-within-8 of chunk
  int schk = (lane & 7) ^ srow8;  // swizzled in-row 16B-chunk index

#define STAGE(buf, ks)                                                          \
  {                                                                             \
    __bf16* kb = &KV[buf][0][0];                                                \
    __bf16* vb = &KV[buf][1][0];                                                \
    _Pragma("unroll") for (int c = 0; c < 2; ++c) {                             \
      int c1kb = w * 2 + c;                                                     \
      int rr = c1kb * 8 + srow8;                                                \
      gload_lds16(Kg + (size_t)((ks) + rr) * 64 + schk * 8, kb + c1kb * 512);   \
      gload_lds16(Vg + (size_t)rr * S + (ks) + schk * 8, vb + c1kb * 512);      \
    }                                                                           \
  }

  STAGE(0, 0);

  int srcA = lmod + ((lane & 16) << 1);
  int srcB = srcA + 16;
  bool tsel = (ldiv < 2);
  int r7 = lmod & 7;
  int ca = ldiv ^ r7;        // swizzled chunk, k-slots 0..31 half
  int cb = (4 + ldiv) ^ r7;  // k-slots 32..63 half

  int cur = 0;
  for (int kt = 0; kt < nkt; ++kt) {
    int ks = kt * 64;
    __syncthreads();  // drains own gload vmcnt (issued one compute-phase ago)
    if (kt + 1 < nkt) STAGE(cur ^ 1, ks + 64);
    const __bf16* Ksb = &KV[cur][0][0];
    const __bf16* Vsb = &KV[cur][1][0];

    // ---- QK^T (swapped): lane holds S[k=t16*16+ldiv*4+r][q=lmod]
    f32x4 st[4] = {};
    __builtin_amdgcn_s_setprio(1);
#pragma unroll
    for (int t16 = 0; t16 < 4; ++t16) {
      int row = t16 * 16 + lmod;
      bf16x8 kf0 = *(const bf16x8*)(Ksb + row * 64 + ca * 8);
      bf16x8 kf1 = *(const bf16x8*)(Ksb + row * 64 + cb * 8);
      st[t16] = MFMA16(kf0, qf0, st[t16]);
      st[t16] = MFMA16(kf1, qf1, st[t16]);
    }
    __builtin_amdgcn_s_setprio(0);

    if (kt == nkt - 1) {  // diagonal tile: causal mask
      int qq = R0 + lmod;
#pragma unroll
      for (int t16 = 0; t16 < 4; ++t16) {
        int kk = ks + t16 * 16 + ldiv * 4;
#pragma unroll
        for (int r = 0; r < 4; ++r)
          st[t16][r] = (kk + r) <= qq ? st[t16][r] : -1e30f;
      }
    }

    // V fragments
    bf16x8 vf[8];
#pragma unroll
    for (int g = 0; g < 4; ++g) {
      int row = g * 16 + lmod;
      vf[g] = *(const bf16x8*)(Vsb + row * 64 + ca * 8);
      vf[4 + g] = *(const bf16x8*)(Vsb + row * 64 + cb * 8);
    }

    // ---- softmax (single q-group)
    float pm = st[0][0];
#pragma unroll
    for (int t16 = 0; t16 < 4; ++t16)
#pragma unroll
      for (int r = 0; r < 4; ++r) pm = fmaxf(pm, st[t16][r]);
    pm = fmaxf(pm, __shfl_xor(pm, 16));
    pm = fmaxf(pm, __shfl_xor(pm, 32));
    float m2n = pm * cs;

    bool grow = !__all(m2n <= m2 + 8.0f);  // defer-max
    float al = 1.0f;
    if (grow) {
      al = exp2f(m2 - m2n);
      m2 = m2n;
    }

    float rs = 0.f;
#pragma unroll
    for (int t16 = 0; t16 < 4; ++t16)
#pragma unroll
      for (int r = 0; r < 4; ++r) {
        float pv = exp2f(st[t16][r] * cs - m2);
        st[t16][r] = pv;
        rs += pv;
      }
    rs += __shfl_xor(rs, 16);
    rs += __shfl_xor(rs, 32);
    lr = lr * al + rs;

    if (grow) {
      float alq[4];
#pragma unroll
      for (int r = 0; r < 4; ++r) alq[r] = __shfl(al, ldiv * 4 + r);
#pragma unroll
      for (int g = 0; g < 4; ++g)
#pragma unroll
        for (int r = 0; r < 4; ++r) acc[g][r] *= alq[r];
    }

    // pack P to bf16 pairs
    uint32_t b0 = pk2(st[0][0], st[0][1]);
    uint32_t b1 = pk2(st[0][2], st[0][3]);
    uint32_t b2 = pk2(st[1][0], st[1][1]);
    uint32_t b3 = pk2(st[1][2], st[1][3]);
    uint32_t b4 = pk2(st[2][0], st[2][1]);
    uint32_t b5 = pk2(st[2][2], st[2][3]);
    uint32_t b6 = pk2(st[3][0], st[3][1]);
    uint32_t b7 = pk2(st[3][2], st[3][3]);

    // redistribute to PV A-fragment layout (within-wave)
    uint32_t x, y;
    u32x4 av0, av1;
    x = (uint32_t)__shfl((int)b0, srcA); y = (uint32_t)__shfl((int)b2, srcA); av0[0] = tsel ? x : y;
    x = (uint32_t)__shfl((int)b1, srcA); y = (uint32_t)__shfl((int)b3, srcA); av0[1] = tsel ? x : y;
    x = (uint32_t)__shfl((int)b0, srcB); y = (uint32_t)__shfl((int)b2, srcB); av0[2] = tsel ? x : y;
    x = (uint32_t)__shfl((int)b1, srcB); y = (uint32_t)__shfl((int)b3, srcB); av0[3] = tsel ? x : y;
    x = (uint32_t)__shfl((int)b4, srcA); y = (uint32_t)__shfl((int)b6, srcA); av1[0] = tsel ? x : y;
    x = (uint32_t)__shfl((int)b5, srcA); y = (uint32_t)__shfl((int)b7, srcA); av1[1] = tsel ? x : y;
    x = (uint32_t)__shfl((int)b4, srcB); y = (uint32_t)__shfl((int)b6, srcB); av1[2] = tsel ? x : y;
    x = (uint32_t)__shfl((int)b5, srcB); y = (uint32_t)__shfl((int)b7, srcB); av1[3] = tsel ? x : y;
    bf16x8 pa0 = __builtin_bit_cast(bf16x8, av0);
    bf16x8 pa1 = __builtin_bit_cast(bf16x8, av1);

    __builtin_amdgcn_s_setprio(1);
#pragma unroll
    for (int g = 0; g < 4; ++g) {
      acc[g] = MFMA16(pa0, vf[g], acc[g]);
      acc[g] = MFMA16(pa1, vf[4 + g], acc[g]);
    }
    __builtin_amdgcn_s_setprio(0);
    cur ^= 1;
  }

  // epilogue
  {
    float linv[4];
#pragma unroll
    for (int r = 0; r < 4; ++r) {
      float lq = __shfl(lr, ldiv * 4 + r);
      linv[r] = 1.0f / lq;
    }
#pragma unroll
    for (int g = 0; g < 4; ++g)
#pragma unroll
      for (int r = 0; r < 4; ++r)
        O[(size_t)(R0 + ldiv * 4 + r) * 2048 + h * 64 + g * 16 + lmod] =
            (__bf16)(acc[g][r] * linv[r]);
  }
}

// ---------------------------------------------------------------- launch
extern "C" void kernel_launch(void* const* d_in, const int* in_sizes, int n_in,
                              void* d_out, int out_size, void* d_ws, size_t ws_size,
                              hipStream_t stream) {
  const float* x = (const float*)d_in[0];
  const float* cosb = (const float*)d_in[1];
  const float* sinb = (const float*)d_in[2];
  const float* wqkv = (const float*)d_in[3];
  const float* wo = (const float*)d_in[4];
  float* out = (float*)d_out;

  char* ws = (char*)d_ws;
  __bf16* xb    = (__bf16*)(ws + 0);
  __bf16* wqkvT = (__bf16*)(ws + 8388608);
  __bf16* woT   = (__bf16*)(ws + 20971520);
  __bf16* qkvb  = (__bf16*)(ws + 29360128);
  __bf16* Krb   = (__bf16*)(ws + 41943040);
  __bf16* Vtb   = (__bf16*)(ws + 44040192);
  __bf16* attnb = (__bf16*)(ws + 46137344);

  cvt_f32_bf16<<<4096, 256, 0, stream>>>(x, xb);
  transpose_f32_bf16<<<dim3(48, 32), 256, 0, stream>>>(wqkv, wqkvT, 2048, 3072);
  transpose_f32_bf16<<<dim3(32, 32), 256, 0, stream>>>(wo, woT, 2048, 2048);
  gemm8<__bf16><<<dim3(24, 16), 512, 0, stream>>>(xb, wqkvT, qkvb, 2048, 3072, 2048);
  rope_restruct<<<dim3(32, 8), 256, 0, stream>>>(qkvb, cosb, sinb, Krb, Vtb);
  attn_fwd<<<dim3(32, 32), 256, 0, stream>>>(qkvb, Krb, Vtb, attnb);
  gemm8<float><<<dim3(16, 16), 512, 0, stream>>>(attnb, woT, out, 2048, 2048, 2048);
}

// Round 5
// 175.322 us; speedup vs baseline: 1.7387x; 1.1174x over previous
//
#include <hip/hip_runtime.h>
#include <hip/hip_bf16.h>
#include <stdint.h>

typedef float f32x4 __attribute__((ext_vector_type(4)));
typedef float f32x4v __attribute__((ext_vector_type(4)));
typedef __bf16 bf16x8 __attribute__((ext_vector_type(8)));
typedef __bf16 bf16x4 __attribute__((ext_vector_type(4)));
typedef __bf16 bf16x2 __attribute__((ext_vector_type(2)));
typedef unsigned int u32x4 __attribute__((ext_vector_type(4)));

#define LOG2E 1.44269504088896340736f
#define MFMA16(a, b, c) __builtin_amdgcn_mfma_f32_16x16x32_bf16((a), (b), (c), 0, 0, 0)

static __device__ __forceinline__ void gload_lds16(const void* g, void* l) {
  __builtin_amdgcn_global_load_lds(
      (const __attribute__((address_space(1))) unsigned int*)g,
      (__attribute__((address_space(3))) unsigned int*)l, 16, 0, 0);
}

static __device__ __forceinline__ uint32_t pk2(float lo, float hi) {
  bf16x2 v;
  v[0] = (__bf16)lo;
  v[1] = (__bf16)hi;
  return __builtin_bit_cast(uint32_t, v);
}

// ---------------------------------------------------------------- converts
__global__ __launch_bounds__(256) void cvt_f32_bf16(const float* __restrict__ in,
                                                    __bf16* __restrict__ out) {
  int i = blockIdx.x * 256 + threadIdx.x;
  f32x4v v = *(const f32x4v*)(in + (size_t)i * 4);
  bf16x4 o;
  o[0] = (__bf16)v[0]; o[1] = (__bf16)v[1]; o[2] = (__bf16)v[2]; o[3] = (__bf16)v[3];
  *(bf16x4*)(out + (size_t)i * 4) = o;
}

// in [R][C] f32 -> out [C][R] bf16, 64x64 tiles
__global__ __launch_bounds__(256) void transpose_f32_bf16(const float* __restrict__ in,
                                                          __bf16* __restrict__ out,
                                                          int R, int C) {
  __shared__ float tile[64][65];
  int tr = blockIdx.y * 64, tc = blockIdx.x * 64;
  int t = threadIdx.x;
  int r0 = t >> 4;
  int c4 = (t & 15) * 4;
#pragma unroll
  for (int i = 0; i < 4; ++i) {
    int r = r0 + i * 16;
    f32x4v v = *(const f32x4v*)(in + (size_t)(tr + r) * C + tc + c4);
    tile[r][c4 + 0] = v[0]; tile[r][c4 + 1] = v[1];
    tile[r][c4 + 2] = v[2]; tile[r][c4 + 3] = v[3];
  }
  __syncthreads();
#pragma unroll
  for (int i = 0; i < 4; ++i) {
    int r = r0 + i * 16;
    __bf16* o = out + (size_t)(tc + r) * R + tr + c4;
    bf16x4 ov;
    ov[0] = (__bf16)tile[c4 + 0][r]; ov[1] = (__bf16)tile[c4 + 1][r];
    ov[2] = (__bf16)tile[c4 + 2][r]; ov[3] = (__bf16)tile[c4 + 3][r];
    *(bf16x4*)o = ov;
  }
}

// ---------------------------------------------------------------- GEMM: 8-wave, 3-buf, counted vmcnt
template <typename OutT>
__global__ __launch_bounds__(512) void gemm8(const __bf16* __restrict__ A,
                                             const __bf16* __restrict__ BT,
                                             OutT* __restrict__ C,
                                             int M, int N, int K) {
  __shared__ alignas(16) __bf16 As[3][4096];
  __shared__ alignas(16) __bf16 Bs[3][4096];
  int bn = blockIdx.x, bm = blockIdx.y;
  int t = threadIdx.x;
  int lane = t & 63, w = t >> 6;  // 8 waves
  int lmod = lane & 15, ldiv = lane >> 4;
  int wr = w >> 1, wc = w & 1;

  f32x4 acc[2][4] = {};

  int srow = lane >> 2;
  int scol = (lane & 3) * 8;
  const __bf16* ga = A + (size_t)(bm * 128 + w * 16 + srow) * K + scol;
  const __bf16* gb = BT + (size_t)(bn * 128 + w * 16 + srow) * K + scol;

#define GSTAGE(b, tt)                                  \
  {                                                    \
    gload_lds16(ga + (tt) * 32, &As[b][w * 512]);      \
    gload_lds16(gb + (tt) * 32, &Bs[b][w * 512]);      \
  }

  int NT = K >> 5;
  GSTAGE(0, 0);
  if (NT > 1) GSTAGE(1, 1);

  int bc = 0, bnx = 2;
  for (int tt = 0; tt < NT; ++tt) {
    if (tt + 2 < NT) {
      GSTAGE(bnx, tt + 2);
      asm volatile("s_waitcnt vmcnt(4)" ::: "memory");
    } else if (tt + 1 < NT) {
      asm volatile("s_waitcnt vmcnt(2)" ::: "memory");
    } else {
      asm volatile("s_waitcnt vmcnt(0)" ::: "memory");
    }
    __builtin_amdgcn_s_barrier();
    __builtin_amdgcn_sched_barrier(0);
    bf16x8 af[2], bfr[4];
#pragma unroll
    for (int i = 0; i < 2; ++i)
      af[i] = *(const bf16x8*)(&As[bc][(wr * 32 + i * 16 + lmod) * 32 + ldiv * 8]);
#pragma unroll
    for (int j = 0; j < 4; ++j)
      bfr[j] = *(const bf16x8*)(&Bs[bc][(wc * 64 + j * 16 + lmod) * 32 + ldiv * 8]);
    __builtin_amdgcn_s_setprio(1);
#pragma unroll
    for (int i = 0; i < 2; ++i)
#pragma unroll
      for (int j = 0; j < 4; ++j)
        acc[i][j] = MFMA16(af[i], bfr[j], acc[i][j]);
    __builtin_amdgcn_s_setprio(0);
    __builtin_amdgcn_sched_barrier(0);
    __builtin_amdgcn_s_barrier();
    bc = (bc == 2) ? 0 : bc + 1;
    bnx = (bnx == 2) ? 0 : bnx + 1;
  }

#pragma unroll
  for (int i = 0; i < 2; ++i) {
    int row0 = bm * 128 + wr * 32 + i * 16 + ldiv * 4;
#pragma unroll
    for (int j = 0; j < 4; ++j) {
      int col = bn * 128 + wc * 64 + j * 16 + lmod;
#pragma unroll
      for (int r = 0; r < 4; ++r)
        C[(size_t)(row0 + r) * N + col] = (OutT)acc[i][j][r];
    }
  }
}

// ---------------------------------------------------------------- RoPE + restructure
// Q is additionally pre-scaled by 0.125*log2e so attention scores come out of
// QK^T directly in log2 domain (softmax shift-invariance makes the max/shift
// unnecessary; exp2 of raw scores stays well inside f32 range).
__global__ __launch_bounds__(256) void rope_restruct(__bf16* __restrict__ qkv,
                                                     const float* __restrict__ cosb,
                                                     const float* __restrict__ sinb,
                                                     __bf16* __restrict__ Kr,
                                                     __bf16* __restrict__ Vt) {
  int st = blockIdx.x * 64;
  int kvh = blockIdx.y;
  int t = threadIdx.x;
  __shared__ alignas(16) __bf16 vtile[64][72];
  const float csq = 0.125f * LOG2E;

  int r = t >> 2;
  int q4 = t & 3;
  int s = st + r;
  const float* cp = cosb + (size_t)s * 32;
  const float* sp = sinb + (size_t)s * 32;

  {
    __bf16* p = qkv + (size_t)s * 3072 + (kvh * 4 + q4) * 64;
#pragma unroll
    for (int d = 0; d < 16; ++d) {
      float x1 = (float)p[d], x2 = (float)p[d + 16];
      float o1 = (x1 * cp[d] - x2 * sp[d]) * csq;
      float o2 = (x2 * cp[d + 16] + x1 * sp[d + 16]) * csq;
      p[d] = (__bf16)o1;
      p[d + 16] = (__bf16)o2;
    }
#pragma unroll
    for (int c = 0; c < 4; ++c) {
      bf16x8 v = *(const bf16x8*)(p + 32 + c * 8);
#pragma unroll
      for (int j = 0; j < 8; ++j) v[j] = (__bf16)((float)v[j] * csq);
      *(bf16x8*)(p + 32 + c * 8) = v;
    }
  }
  {
    const __bf16* p = qkv + (size_t)s * 3072 + 2048 + kvh * 64;
    __bf16* ko = Kr + ((size_t)kvh * 2048 + s) * 64;
    if (q4 == 0) {
#pragma unroll
      for (int d = 0; d < 16; ++d) {
        float x1 = (float)p[d], x2 = (float)p[d + 16];
        ko[d] = (__bf16)(x1 * cp[d] - x2 * sp[d]);
      }
    } else if (q4 == 1) {
#pragma unroll
      for (int d = 0; d < 16; ++d) {
        float x1 = (float)p[d], x2 = (float)p[d + 16];
        ko[d + 16] = (__bf16)(x2 * cp[d + 16] + x1 * sp[d + 16]);
      }
    } else if (q4 == 2) {
      *(bf16x8*)(ko + 32) = *(const bf16x8*)(p + 32);
      *(bf16x8*)(ko + 40) = *(const bf16x8*)(p + 40);
    } else {
      *(bf16x8*)(ko + 48) = *(const bf16x8*)(p + 48);
      *(bf16x8*)(ko + 56) = *(const bf16x8*)(p + 56);
    }
  }
  {
    const __bf16* p = qkv + (size_t)s * 3072 + 2560 + kvh * 64 + q4 * 16;
    *(bf16x8*)&vtile[r][q4 * 16] = *(const bf16x8*)p;
    *(bf16x8*)&vtile[r][q4 * 16 + 8] = *(const bf16x8*)(p + 8);
  }
  __syncthreads();
  {
    int d = t >> 2;
    __bf16* vo = Vt + ((size_t)kvh * 64 + d) * 2048 + st + q4 * 16;
#pragma unroll
    for (int j = 0; j < 16; ++j) vo[j] = vtile[q4 * 16 + j][d];
  }
}

// ---------------------------------------------------------------- flash attention v5
// QBLK=64, 4 waves x 16 q rows, KVBLK=64 dbuf, swapped QK^T, in-reg P,
// shift-free softmax (exp2 only, deferred l-reduction).
__global__ __launch_bounds__(256) void attn_fwd(const __bf16* __restrict__ qkv,
                                                const __bf16* __restrict__ Kr,
                                                const __bf16* __restrict__ Vt,
                                                __bf16* __restrict__ O) {
  const int S = 2048, LDQ = 3072;
  int i = blockIdx.x;
  int qt = (i & 1) ? (i >> 1) : (31 - (i >> 1));  // pairs sum to 31 tile-units
  int h = blockIdx.y;
  int kvh = h >> 2;
  int t = threadIdx.x;
  int lane = t & 63, w = t >> 6;  // 4 waves
  int lmod = lane & 15, ldiv = lane >> 4;

  __shared__ alignas(16) __bf16 KV[2][2][4096];  // [buf][K/V][row*64+col], 32KB

  int R0 = qt * 64 + w * 16;  // this wave's 16 q rows

  const __bf16* qp = qkv + (size_t)(R0 + lmod) * LDQ + h * 64 + ldiv * 8;
  bf16x8 qf0 = *(const bf16x8*)qp;
  bf16x8 qf1 = *(const bf16x8*)(qp + 32);

  f32x4 acc[4] = {};
  f32x4 lacc = {};
  int nkt = qt + 1;

  const __bf16* Kg = Kr + (size_t)kvh * S * 64;
  const __bf16* Vg = Vt + (size_t)kvh * 64 * S;
  int srow8 = lane >> 3;          // row-within-8 of chunk
  int schk = (lane & 7) ^ srow8;  // swizzled in-row 16B-chunk index

#define STAGE(buf, ks)                                                          \
  {                                                                             \
    __bf16* kb = &KV[buf][0][0];                                                \
    __bf16* vb = &KV[buf][1][0];                                                \
    _Pragma("unroll") for (int c = 0; c < 2; ++c) {                             \
      int c1kb = w * 2 + c;                                                     \
      int rr = c1kb * 8 + srow8;                                                \
      gload_lds16(Kg + (size_t)((ks) + rr) * 64 + schk * 8, kb + c1kb * 512);   \
      gload_lds16(Vg + (size_t)rr * S + (ks) + schk * 8, vb + c1kb * 512);      \
    }                                                                           \
  }

  STAGE(0, 0);

  int srcA = lmod + ((lane & 16) << 1);
  int srcB = srcA + 16;
  bool tsel = (ldiv < 2);
  int r7 = lmod & 7;
  int ca = ldiv ^ r7;        // swizzled chunk, k-slots 0..31 half
  int cb = (4 + ldiv) ^ r7;  // k-slots 32..63 half

  int cur = 0;
  for (int kt = 0; kt < nkt; ++kt) {
    int ks = kt * 64;
    __syncthreads();  // drains own gload vmcnt (issued one compute-phase ago)
    if (kt + 1 < nkt) STAGE(cur ^ 1, ks + 64);
    const __bf16* Ksb = &KV[cur][0][0];
    const __bf16* Vsb = &KV[cur][1][0];

    // ---- QK^T (swapped): lane holds S[k=t16*16+ldiv*4+r][q=lmod], log2 domain
    f32x4 st[4] = {};
    __builtin_amdgcn_s_setprio(1);
#pragma unroll
    for (int t16 = 0; t16 < 4; ++t16) {
      int row = t16 * 16 + lmod;
      bf16x8 kf0 = *(const bf16x8*)(Ksb + row * 64 + ca * 8);
      bf16x8 kf1 = *(const bf16x8*)(Ksb + row * 64 + cb * 8);
      st[t16] = MFMA16(kf0, qf0, st[t16]);
      st[t16] = MFMA16(kf1, qf1, st[t16]);
    }
    __builtin_amdgcn_s_setprio(0);

    if (kt == nkt - 1) {  // diagonal tile: causal mask
      int qq = R0 + lmod;
#pragma unroll
      for (int t16 = 0; t16 < 4; ++t16) {
        int kk = ks + t16 * 16 + ldiv * 4;
#pragma unroll
        for (int r = 0; r < 4; ++r)
          st[t16][r] = (kk + r) <= qq ? st[t16][r] : -1e30f;
      }
    }

    // V fragments
    bf16x8 vf[8];
#pragma unroll
    for (int g = 0; g < 4; ++g) {
      int row = g * 16 + lmod;
      vf[g] = *(const bf16x8*)(Vsb + row * 64 + ca * 8);
      vf[4 + g] = *(const bf16x8*)(Vsb + row * 64 + cb * 8);
    }

    // ---- shift-free softmax: p = exp2(st); accumulate per-lane partial sums
#pragma unroll
    for (int t16 = 0; t16 < 4; ++t16)
#pragma unroll
      for (int r = 0; r < 4; ++r) {
        float pv = __builtin_amdgcn_exp2f(st[t16][r]);
        st[t16][r] = pv;
        lacc[r] += pv;
      }

    // pack P to bf16 pairs
    uint32_t b0 = pk2(st[0][0], st[0][1]);
    uint32_t b1 = pk2(st[0][2], st[0][3]);
    uint32_t b2 = pk2(st[1][0], st[1][1]);
    uint32_t b3 = pk2(st[1][2], st[1][3]);
    uint32_t b4 = pk2(st[2][0], st[2][1]);
    uint32_t b5 = pk2(st[2][2], st[2][3]);
    uint32_t b6 = pk2(st[3][0], st[3][1]);
    uint32_t b7 = pk2(st[3][2], st[3][3]);

    // redistribute to PV A-fragment layout (within-wave)
    uint32_t x, y;
    u32x4 av0, av1;
    x = (uint32_t)__shfl((int)b0, srcA); y = (uint32_t)__shfl((int)b2, srcA); av0[0] = tsel ? x : y;
    x = (uint32_t)__shfl((int)b1, srcA); y = (uint32_t)__shfl((int)b3, srcA); av0[1] = tsel ? x : y;
    x = (uint32_t)__shfl((int)b0, srcB); y = (uint32_t)__shfl((int)b2, srcB); av0[2] = tsel ? x : y;
    x = (uint32_t)__shfl((int)b1, srcB); y = (uint32_t)__shfl((int)b3, srcB); av0[3] = tsel ? x : y;
    x = (uint32_t)__shfl((int)b4, srcA); y = (uint32_t)__shfl((int)b6, srcA); av1[0] = tsel ? x : y;
    x = (uint32_t)__shfl((int)b5, srcA); y = (uint32_t)__shfl((int)b7, srcA); av1[1] = tsel ? x : y;
    x = (uint32_t)__shfl((int)b4, srcB); y = (uint32_t)__shfl((int)b6, srcB); av1[2] = tsel ? x : y;
    x = (uint32_t)__shfl((int)b5, srcB); y = (uint32_t)__shfl((int)b7, srcB); av1[3] = tsel ? x : y;
    bf16x8 pa0 = __builtin_bit_cast(bf16x8, av0);
    bf16x8 pa1 = __builtin_bit_cast(bf16x8, av1);

    __builtin_amdgcn_s_setprio(1);
#pragma unroll
    for (int g = 0; g < 4; ++g) {
      acc[g] = MFMA16(pa0, vf[g], acc[g]);
      acc[g] = MFMA16(pa1, vf[4 + g], acc[g]);
    }
    __builtin_amdgcn_s_setprio(0);
    cur ^= 1;
  }

  // epilogue: reduce l across lanes once, then normalize
  {
    float lsum = lacc[0] + lacc[1] + lacc[2] + lacc[3];
    lsum += __shfl_xor(lsum, 16);
    lsum += __shfl_xor(lsum, 32);
    float linv[4];
#pragma unroll
    for (int r = 0; r < 4; ++r) {
      float lq = __shfl(lsum, ldiv * 4 + r);
      linv[r] = 1.0f / lq;
    }
#pragma unroll
    for (int g = 0; g < 4; ++g)
#pragma unroll
      for (int r = 0; r < 4; ++r)
        O[(size_t)(R0 + ldiv * 4 + r) * 2048 + h * 64 + g * 16 + lmod] =
            (__bf16)(acc[g][r] * linv[r]);
  }
}

// ---------------------------------------------------------------- launch
extern "C" void kernel_launch(void* const* d_in, const int* in_sizes, int n_in,
                              void* d_out, int out_size, void* d_ws, size_t ws_size,
                              hipStream_t stream) {
  const float* x = (const float*)d_in[0];
  const float* cosb = (const float*)d_in[1];
  const float* sinb = (const float*)d_in[2];
  const float* wqkv = (const float*)d_in[3];
  const float* wo = (const float*)d_in[4];
  float* out = (float*)d_out;

  char* ws = (char*)d_ws;
  __bf16* xb    = (__bf16*)(ws + 0);
  __bf16* wqkvT = (__bf16*)(ws + 8388608);
  __bf16* woT   = (__bf16*)(ws + 20971520);
  __bf16* qkvb  = (__bf16*)(ws + 29360128);
  __bf16* Krb   = (__bf16*)(ws + 41943040);
  __bf16* Vtb   = (__bf16*)(ws + 44040192);
  __bf16* attnb = (__bf16*)(ws + 46137344);

  cvt_f32_bf16<<<4096, 256, 0, stream>>>(x, xb);
  transpose_f32_bf16<<<dim3(48, 32), 256, 0, stream>>>(wqkv, wqkvT, 2048, 3072);
  transpose_f32_bf16<<<dim3(32, 32), 256, 0, stream>>>(wo, woT, 2048, 2048);
  gemm8<__bf16><<<dim3(24, 16), 512, 0, stream>>>(xb, wqkvT, qkvb, 2048, 3072, 2048);
  rope_restruct<<<dim3(32, 8), 256, 0, stream>>>(qkvb, cosb, sinb, Krb, Vtb);
  attn_fwd<<<dim3(32, 32), 256, 0, stream>>>(qkvb, Krb, Vtb, attnb);
  gemm8<float><<<dim3(16, 16), 512, 0, stream>>>(attnb, woT, out, 2048, 2048, 2048);
}

// Round 6
// 164.409 us; speedup vs baseline: 1.8541x; 1.0664x over previous
//
#include <hip/hip_runtime.h>
#include <hip/hip_bf16.h>
#include <stdint.h>

typedef float f32x4 __attribute__((ext_vector_type(4)));
typedef float f32x4v __attribute__((ext_vector_type(4)));
typedef __bf16 bf16x8 __attribute__((ext_vector_type(8)));
typedef __bf16 bf16x4 __attribute__((ext_vector_type(4)));
typedef __bf16 bf16x2 __attribute__((ext_vector_type(2)));
typedef unsigned int u32x4 __attribute__((ext_vector_type(4)));

#define LOG2E 1.44269504088896340736f
#define MFMA16(a, b, c) __builtin_amdgcn_mfma_f32_16x16x32_bf16((a), (b), (c), 0, 0, 0)

static __device__ __forceinline__ void gload_lds16(const void* g, void* l) {
  __builtin_amdgcn_global_load_lds(
      (const __attribute__((address_space(1))) unsigned int*)g,
      (__attribute__((address_space(3))) unsigned int*)l, 16, 0, 0);
}

static __device__ __forceinline__ uint32_t pk2(float lo, float hi) {
  bf16x2 v;
  v[0] = (__bf16)lo;
  v[1] = (__bf16)hi;
  return __builtin_bit_cast(uint32_t, v);
}

// ---------------------------------------------------------------- converts
__global__ __launch_bounds__(256) void cvt_f32_bf16(const float* __restrict__ in,
                                                    __bf16* __restrict__ out) {
  int i = blockIdx.x * 256 + threadIdx.x;
  f32x4v v = *(const f32x4v*)(in + (size_t)i * 4);
  bf16x4 o;
  o[0] = (__bf16)v[0]; o[1] = (__bf16)v[1]; o[2] = (__bf16)v[2]; o[3] = (__bf16)v[3];
  *(bf16x4*)(out + (size_t)i * 4) = o;
}

// in [R][C] f32 -> out [C][R] bf16, 64x64 tiles
__global__ __launch_bounds__(256) void transpose_f32_bf16(const float* __restrict__ in,
                                                          __bf16* __restrict__ out,
                                                          int R, int C) {
  __shared__ float tile[64][65];
  int tr = blockIdx.y * 64, tc = blockIdx.x * 64;
  int t = threadIdx.x;
  int r0 = t >> 4;
  int c4 = (t & 15) * 4;
#pragma unroll
  for (int i = 0; i < 4; ++i) {
    int r = r0 + i * 16;
    f32x4v v = *(const f32x4v*)(in + (size_t)(tr + r) * C + tc + c4);
    tile[r][c4 + 0] = v[0]; tile[r][c4 + 1] = v[1];
    tile[r][c4 + 2] = v[2]; tile[r][c4 + 3] = v[3];
  }
  __syncthreads();
#pragma unroll
  for (int i = 0; i < 4; ++i) {
    int r = r0 + i * 16;
    __bf16* o = out + (size_t)(tc + r) * R + tr + c4;
    bf16x4 ov;
    ov[0] = (__bf16)tile[c4 + 0][r]; ov[1] = (__bf16)tile[c4 + 1][r];
    ov[2] = (__bf16)tile[c4 + 2][r]; ov[3] = (__bf16)tile[c4 + 3][r];
    *(bf16x4*)o = ov;
  }
}

// ---------------------------------------------------------------- GEMM v3: 4-wave, BK=64, dbuf,
// XOR-swizzled LDS (chunk16 ^= row&7 via pre-swizzled global source + swizzled reads).
// C[M][N] = A[M][K] * BT[N][K]^T. 128x128 tile, wave w owns 64x64 quadrant.
template <typename OutT>
__global__ __launch_bounds__(256) void gemm4(const __bf16* __restrict__ A,
                                             const __bf16* __restrict__ BT,
                                             OutT* __restrict__ C,
                                             int M, int N, int K) {
  __shared__ alignas(16) __bf16 As[2][128 * 64];  // 16KB each buf
  __shared__ alignas(16) __bf16 Bs[2][128 * 64];
  int bn = blockIdx.x, bm = blockIdx.y;
  int t = threadIdx.x;
  int lane = t & 63, w = t >> 6;  // 4 waves
  int lmod = lane & 15, ldiv = lane >> 4;
  int wr = w >> 1, wc = w & 1;

  f32x4 acc[4][4] = {};

  // staging: wave w stages 1KB chunks {w, w+4, w+8, w+12} of each 16KB buffer.
  // LDS linear [row][64]; global source chunk pre-swizzled: chunk ^= (row&7).
  int sr8 = lane >> 3;            // row-within-8
  int sk = (lane & 7) ^ sr8;      // swizzled 16B-chunk within row
  const __bf16* gaB[4];
  const __bf16* gbB[4];
#pragma unroll
  for (int c = 0; c < 4; ++c) {
    int rr = (c * 4 + w) * 8 + sr8;
    gaB[c] = A + (size_t)(bm * 128 + rr) * K + sk * 8;
    gbB[c] = BT + (size_t)(bn * 128 + rr) * K + sk * 8;
  }

#define GSTAGE(buf, k0)                                              \
  {                                                                  \
    _Pragma("unroll") for (int c = 0; c < 4; ++c) {                  \
      gload_lds16(gaB[c] + (k0), &As[buf][(c * 4 + w) * 512]);       \
      gload_lds16(gbB[c] + (k0), &Bs[buf][(c * 4 + w) * 512]);       \
    }                                                                \
  }

  int ca = ldiv ^ (lmod & 7);        // swizzled chunk for k 0..31
  int cb = (4 + ldiv) ^ (lmod & 7);  // k 32..63

  int NT = K >> 6;
  GSTAGE(0, 0);
  int cur = 0;
  for (int tt = 0; tt < NT; ++tt) {
    asm volatile("s_waitcnt vmcnt(0)" ::: "memory");
    __builtin_amdgcn_s_barrier();
    __builtin_amdgcn_sched_barrier(0);
    if (tt + 1 < NT) GSTAGE(cur ^ 1, (tt + 1) * 64);

    bf16x8 af[4][2], bfv[4][2];
#pragma unroll
    for (int i = 0; i < 4; ++i) {
      const __bf16* p = &As[cur][(wr * 64 + i * 16 + lmod) * 64];
      af[i][0] = *(const bf16x8*)(p + ca * 8);
      af[i][1] = *(const bf16x8*)(p + cb * 8);
    }
#pragma unroll
    for (int j = 0; j < 4; ++j) {
      const __bf16* p = &Bs[cur][(wc * 64 + j * 16 + lmod) * 64];
      bfv[j][0] = *(const bf16x8*)(p + ca * 8);
      bfv[j][1] = *(const bf16x8*)(p + cb * 8);
    }
    __builtin_amdgcn_s_setprio(1);
#pragma unroll
    for (int i = 0; i < 4; ++i)
#pragma unroll
      for (int j = 0; j < 4; ++j) {
        acc[i][j] = MFMA16(af[i][0], bfv[j][0], acc[i][j]);
        acc[i][j] = MFMA16(af[i][1], bfv[j][1], acc[i][j]);
      }
    __builtin_amdgcn_s_setprio(0);
    __builtin_amdgcn_sched_barrier(0);
    cur ^= 1;
  }

#pragma unroll
  for (int i = 0; i < 4; ++i) {
    int row0 = bm * 128 + wr * 64 + i * 16 + ldiv * 4;
#pragma unroll
    for (int j = 0; j < 4; ++j) {
      int col = bn * 128 + wc * 64 + j * 16 + lmod;
#pragma unroll
      for (int r = 0; r < 4; ++r)
        C[(size_t)(row0 + r) * N + col] = (OutT)acc[i][j][r];
    }
  }
}

// ---------------------------------------------------------------- RoPE + restructure
// Q pre-scaled by 0.125*log2e (scores come out of QK^T in log2 domain).
__global__ __launch_bounds__(256) void rope_restruct(__bf16* __restrict__ qkv,
                                                     const float* __restrict__ cosb,
                                                     const float* __restrict__ sinb,
                                                     __bf16* __restrict__ Kr,
                                                     __bf16* __restrict__ Vt) {
  int st = blockIdx.x * 64;
  int kvh = blockIdx.y;
  int t = threadIdx.x;
  __shared__ alignas(16) __bf16 vtile[64][72];
  const float csq = 0.125f * LOG2E;

  int r = t >> 2;
  int q4 = t & 3;
  int s = st + r;
  const float* cp = cosb + (size_t)s * 32;
  const float* sp = sinb + (size_t)s * 32;

  {
    __bf16* p = qkv + (size_t)s * 3072 + (kvh * 4 + q4) * 64;
#pragma unroll
    for (int d = 0; d < 16; ++d) {
      float x1 = (float)p[d], x2 = (float)p[d + 16];
      float o1 = (x1 * cp[d] - x2 * sp[d]) * csq;
      float o2 = (x2 * cp[d + 16] + x1 * sp[d + 16]) * csq;
      p[d] = (__bf16)o1;
      p[d + 16] = (__bf16)o2;
    }
#pragma unroll
    for (int c = 0; c < 4; ++c) {
      bf16x8 v = *(const bf16x8*)(p + 32 + c * 8);
#pragma unroll
      for (int j = 0; j < 8; ++j) v[j] = (__bf16)((float)v[j] * csq);
      *(bf16x8*)(p + 32 + c * 8) = v;
    }
  }
  {
    const __bf16* p = qkv + (size_t)s * 3072 + 2048 + kvh * 64;
    __bf16* ko = Kr + ((size_t)kvh * 2048 + s) * 64;
    if (q4 == 0) {
#pragma unroll
      for (int d = 0; d < 16; ++d) {
        float x1 = (float)p[d], x2 = (float)p[d + 16];
        ko[d] = (__bf16)(x1 * cp[d] - x2 * sp[d]);
      }
    } else if (q4 == 1) {
#pragma unroll
      for (int d = 0; d < 16; ++d) {
        float x1 = (float)p[d], x2 = (float)p[d + 16];
        ko[d + 16] = (__bf16)(x2 * cp[d + 16] + x1 * sp[d + 16]);
      }
    } else if (q4 == 2) {
      *(bf16x8*)(ko + 32) = *(const bf16x8*)(p + 32);
      *(bf16x8*)(ko + 40) = *(const bf16x8*)(p + 40);
    } else {
      *(bf16x8*)(ko + 48) = *(const bf16x8*)(p + 48);
      *(bf16x8*)(ko + 56) = *(const bf16x8*)(p + 56);
    }
  }
  {
    const __bf16* p = qkv + (size_t)s * 3072 + 2560 + kvh * 64 + q4 * 16;
    *(bf16x8*)&vtile[r][q4 * 16] = *(const bf16x8*)p;
    *(bf16x8*)&vtile[r][q4 * 16 + 8] = *(const bf16x8*)(p + 8);
  }
  __syncthreads();
  {
    int d = t >> 2;
    __bf16* vo = Vt + ((size_t)kvh * 64 + d) * 2048 + st + q4 * 16;
#pragma unroll
    for (int j = 0; j < 16; ++j) vo[j] = vtile[q4 * 16 + j][d];
  }
}

// ---------------------------------------------------------------- flash attention v5
// QBLK=64, 4 waves x 16 q rows, KVBLK=64 dbuf, swapped QK^T, in-reg P,
// shift-free softmax (exp2 only, deferred l-reduction).
__global__ __launch_bounds__(256) void attn_fwd(const __bf16* __restrict__ qkv,
                                                const __bf16* __restrict__ Kr,
                                                const __bf16* __restrict__ Vt,
                                                __bf16* __restrict__ O) {
  const int S = 2048, LDQ = 3072;
  int i = blockIdx.x;
  int qt = (i & 1) ? (i >> 1) : (31 - (i >> 1));  // pairs sum to 31 tile-units
  int h = blockIdx.y;
  int kvh = h >> 2;
  int t = threadIdx.x;
  int lane = t & 63, w = t >> 6;  // 4 waves
  int lmod = lane & 15, ldiv = lane >> 4;

  __shared__ alignas(16) __bf16 KV[2][2][4096];  // [buf][K/V][row*64+col], 32KB

  int R0 = qt * 64 + w * 16;  // this wave's 16 q rows

  const __bf16* qp = qkv + (size_t)(R0 + lmod) * LDQ + h * 64 + ldiv * 8;
  bf16x8 qf0 = *(const bf16x8*)qp;
  bf16x8 qf1 = *(const bf16x8*)(qp + 32);

  f32x4 acc[4] = {};
  f32x4 lacc = {};
  int nkt = qt + 1;

  const __bf16* Kg = Kr + (size_t)kvh * S * 64;
  const __bf16* Vg = Vt + (size_t)kvh * 64 * S;
  int srow8 = lane >> 3;          // row-within-8 of chunk
  int schk = (lane & 7) ^ srow8;  // swizzled in-row 16B-chunk index

#define STAGE(buf, ks)                                                          \
  {                                                                             \
    __bf16* kb = &KV[buf][0][0];                                                \
    __bf16* vb = &KV[buf][1][0];                                                \
    _Pragma("unroll") for (int c = 0; c < 2; ++c) {                             \
      int c1kb = w * 2 + c;                                                     \
      int rr = c1kb * 8 + srow8;                                                \
      gload_lds16(Kg + (size_t)((ks) + rr) * 64 + schk * 8, kb + c1kb * 512);   \
      gload_lds16(Vg + (size_t)rr * S + (ks) + schk * 8, vb + c1kb * 512);      \
    }                                                                           \
  }

  STAGE(0, 0);

  int srcA = lmod + ((lane & 16) << 1);
  int srcB = srcA + 16;
  bool tsel = (ldiv < 2);
  int r7 = lmod & 7;
  int ca = ldiv ^ r7;        // swizzled chunk, k-slots 0..31 half
  int cb = (4 + ldiv) ^ r7;  // k-slots 32..63 half

  int cur = 0;
  for (int kt = 0; kt < nkt; ++kt) {
    int ks = kt * 64;
    __syncthreads();  // drains own gload vmcnt (issued one compute-phase ago)
    if (kt + 1 < nkt) STAGE(cur ^ 1, ks + 64);
    const __bf16* Ksb = &KV[cur][0][0];
    const __bf16* Vsb = &KV[cur][1][0];

    // ---- QK^T (swapped): lane holds S[k=t16*16+ldiv*4+r][q=lmod], log2 domain
    f32x4 st[4] = {};
    __builtin_amdgcn_s_setprio(1);
#pragma unroll
    for (int t16 = 0; t16 < 4; ++t16) {
      int row = t16 * 16 + lmod;
      bf16x8 kf0 = *(const bf16x8*)(Ksb + row * 64 + ca * 8);
      bf16x8 kf1 = *(const bf16x8*)(Ksb + row * 64 + cb * 8);
      st[t16] = MFMA16(kf0, qf0, st[t16]);
      st[t16] = MFMA16(kf1, qf1, st[t16]);
    }
    __builtin_amdgcn_s_setprio(0);

    if (kt == nkt - 1) {  // diagonal tile: causal mask
      int qq = R0 + lmod;
#pragma unroll
      for (int t16 = 0; t16 < 4; ++t16) {
        int kk = ks + t16 * 16 + ldiv * 4;
#pragma unroll
        for (int r = 0; r < 4; ++r)
          st[t16][r] = (kk + r) <= qq ? st[t16][r] : -1e30f;
      }
    }

    // V fragments
    bf16x8 vf[8];
#pragma unroll
    for (int g = 0; g < 4; ++g) {
      int row = g * 16 + lmod;
      vf[g] = *(const bf16x8*)(Vsb + row * 64 + ca * 8);
      vf[4 + g] = *(const bf16x8*)(Vsb + row * 64 + cb * 8);
    }

    // ---- shift-free softmax: p = exp2(st); per-lane partial sums
#pragma unroll
    for (int t16 = 0; t16 < 4; ++t16)
#pragma unroll
      for (int r = 0; r < 4; ++r) {
        float pv = __builtin_amdgcn_exp2f(st[t16][r]);
        st[t16][r] = pv;
        lacc[r] += pv;
      }

    // pack P to bf16 pairs
    uint32_t b0 = pk2(st[0][0], st[0][1]);
    uint32_t b1 = pk2(st[0][2], st[0][3]);
    uint32_t b2 = pk2(st[1][0], st[1][1]);
    uint32_t b3 = pk2(st[1][2], st[1][3]);
    uint32_t b4 = pk2(st[2][0], st[2][1]);
    uint32_t b5 = pk2(st[2][2], st[2][3]);
    uint32_t b6 = pk2(st[3][0], st[3][1]);
    uint32_t b7 = pk2(st[3][2], st[3][3]);

    // redistribute to PV A-fragment layout (within-wave)
    uint32_t x, y;
    u32x4 av0, av1;
    x = (uint32_t)__shfl((int)b0, srcA); y = (uint32_t)__shfl((int)b2, srcA); av0[0] = tsel ? x : y;
    x = (uint32_t)__shfl((int)b1, srcA); y = (uint32_t)__shfl((int)b3, srcA); av0[1] = tsel ? x : y;
    x = (uint32_t)__shfl((int)b0, srcB); y = (uint32_t)__shfl((int)b2, srcB); av0[2] = tsel ? x : y;
    x = (uint32_t)__shfl((int)b1, srcB); y = (uint32_t)__shfl((int)b3, srcB); av0[3] = tsel ? x : y;
    x = (uint32_t)__shfl((int)b4, srcA); y = (uint32_t)__shfl((int)b6, srcA); av1[0] = tsel ? x : y;
    x = (uint32_t)__shfl((int)b5, srcA); y = (uint32_t)__shfl((int)b7, srcA); av1[1] = tsel ? x : y;
    x = (uint32_t)__shfl((int)b4, srcB); y = (uint32_t)__shfl((int)b6, srcB); av1[2] = tsel ? x : y;
    x = (uint32_t)__shfl((int)b5, srcB); y = (uint32_t)__shfl((int)b7, srcB); av1[3] = tsel ? x : y;
    bf16x8 pa0 = __builtin_bit_cast(bf16x8, av0);
    bf16x8 pa1 = __builtin_bit_cast(bf16x8, av1);

    __builtin_amdgcn_s_setprio(1);
#pragma unroll
    for (int g = 0; g < 4; ++g) {
      acc[g] = MFMA16(pa0, vf[g], acc[g]);
      acc[g] = MFMA16(pa1, vf[4 + g], acc[g]);
    }
    __builtin_amdgcn_s_setprio(0);
    cur ^= 1;
  }

  // epilogue: reduce l across lanes once, then normalize
  {
    float lsum = lacc[0] + lacc[1] + lacc[2] + lacc[3];
    lsum += __shfl_xor(lsum, 16);
    lsum += __shfl_xor(lsum, 32);
    float linv[4];
#pragma unroll
    for (int r = 0; r < 4; ++r) {
      float lq = __shfl(lsum, ldiv * 4 + r);
      linv[r] = 1.0f / lq;
    }
#pragma unroll
    for (int g = 0; g < 4; ++g)
#pragma unroll
      for (int r = 0; r < 4; ++r)
        O[(size_t)(R0 + ldiv * 4 + r) * 2048 + h * 64 + g * 16 + lmod] =
            (__bf16)(acc[g][r] * linv[r]);
  }
}

// ---------------------------------------------------------------- launch
extern "C" void kernel_launch(void* const* d_in, const int* in_sizes, int n_in,
                              void* d_out, int out_size, void* d_ws, size_t ws_size,
                              hipStream_t stream) {
  const float* x = (const float*)d_in[0];
  const float* cosb = (const float*)d_in[1];
  const float* sinb = (const float*)d_in[2];
  const float* wqkv = (const float*)d_in[3];
  const float* wo = (const float*)d_in[4];
  float* out = (float*)d_out;

  char* ws = (char*)d_ws;
  __bf16* xb    = (__bf16*)(ws + 0);
  __bf16* wqkvT = (__bf16*)(ws + 8388608);
  __bf16* woT   = (__bf16*)(ws + 20971520);
  __bf16* qkvb  = (__bf16*)(ws + 29360128);
  __bf16* Krb   = (__bf16*)(ws + 41943040);
  __bf16* Vtb   = (__bf16*)(ws + 44040192);
  __bf16* attnb = (__bf16*)(ws + 46137344);

  cvt_f32_bf16<<<4096, 256, 0, stream>>>(x, xb);
  transpose_f32_bf16<<<dim3(48, 32), 256, 0, stream>>>(wqkv, wqkvT, 2048, 3072);
  transpose_f32_bf16<<<dim3(32, 32), 256, 0, stream>>>(wo, woT, 2048, 2048);
  gemm4<__bf16><<<dim3(24, 16), 256, 0, stream>>>(xb, wqkvT, qkvb, 2048, 3072, 2048);
  rope_restruct<<<dim3(32, 8), 256, 0, stream>>>(qkvb, cosb, sinb, Krb, Vtb);
  attn_fwd<<<dim3(32, 32), 256, 0, stream>>>(qkvb, Krb, Vtb, attnb);
  gemm4<float><<<dim3(16, 16), 256, 0, stream>>>(attnb, woT, out, 2048, 2048, 2048);
}

// Round 7
// 142.474 us; speedup vs baseline: 2.1396x; 1.1540x over previous
//
#include <hip/hip_runtime.h>
#include <hip/hip_bf16.h>
#include <stdint.h>

typedef float f32x4 __attribute__((ext_vector_type(4)));
typedef float f32x4v __attribute__((ext_vector_type(4)));
typedef __bf16 bf16x8 __attribute__((ext_vector_type(8)));
typedef __bf16 bf16x4 __attribute__((ext_vector_type(4)));
typedef __bf16 bf16x2 __attribute__((ext_vector_type(2)));
typedef unsigned int u32x4 __attribute__((ext_vector_type(4)));

#define LOG2E 1.44269504088896340736f
#define MFMA16(a, b, c) __builtin_amdgcn_mfma_f32_16x16x32_bf16((a), (b), (c), 0, 0, 0)

static __device__ __forceinline__ void gload_lds16(const void* g, void* l) {
  __builtin_amdgcn_global_load_lds(
      (const __attribute__((address_space(1))) unsigned int*)g,
      (__attribute__((address_space(3))) unsigned int*)l, 16, 0, 0);
}

static __device__ __forceinline__ uint32_t pk2(float lo, float hi) {
  bf16x2 v;
  v[0] = (__bf16)lo;
  v[1] = (__bf16)hi;
  return __builtin_bit_cast(uint32_t, v);
}

// ---------------------------------------------------------------- converts
__global__ __launch_bounds__(256) void cvt_f32_bf16(const float* __restrict__ in,
                                                    __bf16* __restrict__ out) {
  int i = blockIdx.x * 256 + threadIdx.x;
  f32x4v v = *(const f32x4v*)(in + (size_t)i * 4);
  bf16x4 o;
  o[0] = (__bf16)v[0]; o[1] = (__bf16)v[1]; o[2] = (__bf16)v[2]; o[3] = (__bf16)v[3];
  *(bf16x4*)(out + (size_t)i * 4) = o;
}

// in [R][C] f32 -> out [C][R] bf16, 64x64 tiles
__global__ __launch_bounds__(256) void transpose_f32_bf16(const float* __restrict__ in,
                                                          __bf16* __restrict__ out,
                                                          int R, int C) {
  __shared__ float tile[64][65];
  int tr = blockIdx.y * 64, tc = blockIdx.x * 64;
  int t = threadIdx.x;
  int r0 = t >> 4;
  int c4 = (t & 15) * 4;
#pragma unroll
  for (int i = 0; i < 4; ++i) {
    int r = r0 + i * 16;
    f32x4v v = *(const f32x4v*)(in + (size_t)(tr + r) * C + tc + c4);
    tile[r][c4 + 0] = v[0]; tile[r][c4 + 1] = v[1];
    tile[r][c4 + 2] = v[2]; tile[r][c4 + 3] = v[3];
  }
  __syncthreads();
#pragma unroll
  for (int i = 0; i < 4; ++i) {
    int r = r0 + i * 16;
    __bf16* o = out + (size_t)(tc + r) * R + tr + c4;
    bf16x4 ov;
    ov[0] = (__bf16)tile[c4 + 0][r]; ov[1] = (__bf16)tile[c4 + 1][r];
    ov[2] = (__bf16)tile[c4 + 2][r]; ov[3] = (__bf16)tile[c4 + 3][r];
    *(bf16x4*)o = ov;
  }
}

// ---------------------------------------------------------------- GEMM v3: 4-wave, BK=64, dbuf,
// XOR-swizzled LDS (chunk16 ^= row&7 via pre-swizzled global source + swizzled reads).
template <typename OutT>
__global__ __launch_bounds__(256) void gemm4(const __bf16* __restrict__ A,
                                             const __bf16* __restrict__ BT,
                                             OutT* __restrict__ C,
                                             int M, int N, int K) {
  __shared__ alignas(16) __bf16 As[2][128 * 64];
  __shared__ alignas(16) __bf16 Bs[2][128 * 64];
  int bn = blockIdx.x, bm = blockIdx.y;
  int t = threadIdx.x;
  int lane = t & 63, w = t >> 6;  // 4 waves
  int lmod = lane & 15, ldiv = lane >> 4;
  int wr = w >> 1, wc = w & 1;

  f32x4 acc[4][4] = {};

  int sr8 = lane >> 3;
  int sk = (lane & 7) ^ sr8;
  const __bf16* gaB[4];
  const __bf16* gbB[4];
#pragma unroll
  for (int c = 0; c < 4; ++c) {
    int rr = (c * 4 + w) * 8 + sr8;
    gaB[c] = A + (size_t)(bm * 128 + rr) * K + sk * 8;
    gbB[c] = BT + (size_t)(bn * 128 + rr) * K + sk * 8;
  }

#define GSTAGE(buf, k0)                                              \
  {                                                                  \
    _Pragma("unroll") for (int c = 0; c < 4; ++c) {                  \
      gload_lds16(gaB[c] + (k0), &As[buf][(c * 4 + w) * 512]);       \
      gload_lds16(gbB[c] + (k0), &Bs[buf][(c * 4 + w) * 512]);       \
    }                                                                \
  }

  int ca = ldiv ^ (lmod & 7);
  int cb = (4 + ldiv) ^ (lmod & 7);

  int NT = K >> 6;
  GSTAGE(0, 0);
  int cur = 0;
  for (int tt = 0; tt < NT; ++tt) {
    asm volatile("s_waitcnt vmcnt(0)" ::: "memory");
    __builtin_amdgcn_s_barrier();
    __builtin_amdgcn_sched_barrier(0);
    if (tt + 1 < NT) GSTAGE(cur ^ 1, (tt + 1) * 64);

    bf16x8 af[4][2], bfv[4][2];
#pragma unroll
    for (int i = 0; i < 4; ++i) {
      const __bf16* p = &As[cur][(wr * 64 + i * 16 + lmod) * 64];
      af[i][0] = *(const bf16x8*)(p + ca * 8);
      af[i][1] = *(const bf16x8*)(p + cb * 8);
    }
#pragma unroll
    for (int j = 0; j < 4; ++j) {
      const __bf16* p = &Bs[cur][(wc * 64 + j * 16 + lmod) * 64];
      bfv[j][0] = *(const bf16x8*)(p + ca * 8);
      bfv[j][1] = *(const bf16x8*)(p + cb * 8);
    }
    __builtin_amdgcn_s_setprio(1);
#pragma unroll
    for (int i = 0; i < 4; ++i)
#pragma unroll
      for (int j = 0; j < 4; ++j) {
        acc[i][j] = MFMA16(af[i][0], bfv[j][0], acc[i][j]);
        acc[i][j] = MFMA16(af[i][1], bfv[j][1], acc[i][j]);
      }
    __builtin_amdgcn_s_setprio(0);
    __builtin_amdgcn_sched_barrier(0);
    cur ^= 1;
  }

#pragma unroll
  for (int i = 0; i < 4; ++i) {
    int row0 = bm * 128 + wr * 64 + i * 16 + ldiv * 4;
#pragma unroll
    for (int j = 0; j < 4; ++j) {
      int col = bn * 128 + wc * 64 + j * 16 + lmod;
#pragma unroll
      for (int r = 0; r < 4; ++r)
        C[(size_t)(row0 + r) * N + col] = (OutT)acc[i][j][r];
    }
  }
}

// ---------------------------------------------------------------- RoPE + restructure
// Q pre-scaled by 0.125*log2e (scores come out of QK^T in log2 domain).
__global__ __launch_bounds__(256) void rope_restruct(__bf16* __restrict__ qkv,
                                                     const float* __restrict__ cosb,
                                                     const float* __restrict__ sinb,
                                                     __bf16* __restrict__ Kr,
                                                     __bf16* __restrict__ Vt) {
  int st = blockIdx.x * 64;
  int kvh = blockIdx.y;
  int t = threadIdx.x;
  __shared__ alignas(16) __bf16 vtile[64][72];
  const float csq = 0.125f * LOG2E;

  int r = t >> 2;
  int q4 = t & 3;
  int s = st + r;
  const float* cp = cosb + (size_t)s * 32;
  const float* sp = sinb + (size_t)s * 32;

  {
    __bf16* p = qkv + (size_t)s * 3072 + (kvh * 4 + q4) * 64;
#pragma unroll
    for (int d = 0; d < 16; ++d) {
      float x1 = (float)p[d], x2 = (float)p[d + 16];
      float o1 = (x1 * cp[d] - x2 * sp[d]) * csq;
      float o2 = (x2 * cp[d + 16] + x1 * sp[d + 16]) * csq;
      p[d] = (__bf16)o1;
      p[d + 16] = (__bf16)o2;
    }
#pragma unroll
    for (int c = 0; c < 4; ++c) {
      bf16x8 v = *(const bf16x8*)(p + 32 + c * 8);
#pragma unroll
      for (int j = 0; j < 8; ++j) v[j] = (__bf16)((float)v[j] * csq);
      *(bf16x8*)(p + 32 + c * 8) = v;
    }
  }
  {
    const __bf16* p = qkv + (size_t)s * 3072 + 2048 + kvh * 64;
    __bf16* ko = Kr + ((size_t)kvh * 2048 + s) * 64;
    if (q4 == 0) {
#pragma unroll
      for (int d = 0; d < 16; ++d) {
        float x1 = (float)p[d], x2 = (float)p[d + 16];
        ko[d] = (__bf16)(x1 * cp[d] - x2 * sp[d]);
      }
    } else if (q4 == 1) {
#pragma unroll
      for (int d = 0; d < 16; ++d) {
        float x1 = (float)p[d], x2 = (float)p[d + 16];
        ko[d + 16] = (__bf16)(x2 * cp[d + 16] + x1 * sp[d + 16]);
      }
    } else if (q4 == 2) {
      *(bf16x8*)(ko + 32) = *(const bf16x8*)(p + 32);
      *(bf16x8*)(ko + 40) = *(const bf16x8*)(p + 40);
    } else {
      *(bf16x8*)(ko + 48) = *(const bf16x8*)(p + 48);
      *(bf16x8*)(ko + 56) = *(const bf16x8*)(p + 56);
    }
  }
  {
    const __bf16* p = qkv + (size_t)s * 3072 + 2560 + kvh * 64 + q4 * 16;
    *(bf16x8*)&vtile[r][q4 * 16] = *(const bf16x8*)p;
    *(bf16x8*)&vtile[r][q4 * 16 + 8] = *(const bf16x8*)(p + 8);
  }
  __syncthreads();
  {
    int d = t >> 2;
    __bf16* vo = Vt + ((size_t)kvh * 64 + d) * 2048 + st + q4 * 16;
#pragma unroll
    for (int j = 0; j < 16; ++j) vo[j] = vtile[q4 * 16 + j][d];
  }
}

// ---------------------------------------------------------------- flash attention v6
// QBLK=64, 4 waves x 16 q rows, KVBLK=64 dbuf, swapped QK^T, shift-free softmax,
// pi-permuted K staging: P registers ARE the PV A-fragment (zero cross-lane ops).
// pi(rho) = 32*r5 + 16*r3 + 8*r2 + 4*r4 + 2*r1 + r0  (K-row stored at LDS row rho).
__global__ __launch_bounds__(256) void attn_fwd(const __bf16* __restrict__ qkv,
                                                const __bf16* __restrict__ Kr,
                                                const __bf16* __restrict__ Vt,
                                                __bf16* __restrict__ O) {
  const int S = 2048, LDQ = 3072;
  int i = blockIdx.x;
  int qt = (i & 1) ? (i >> 1) : (31 - (i >> 1));  // pairs sum to 31 tile-units
  int h = blockIdx.y;
  int kvh = h >> 2;
  int t = threadIdx.x;
  int lane = t & 63, w = t >> 6;  // 4 waves
  int lmod = lane & 15, ldiv = lane >> 4;

  __shared__ alignas(16) __bf16 KV[2][2][4096];  // [buf][K/V][row*64+col], 32KB

  int R0 = qt * 64 + w * 16;  // this wave's 16 q rows

  const __bf16* qp = qkv + (size_t)(R0 + lmod) * LDQ + h * 64 + ldiv * 8;
  bf16x8 qf0 = *(const bf16x8*)qp;
  bf16x8 qf1 = *(const bf16x8*)(qp + 32);

  f32x4 acc[4] = {};
  f32x4 lacc = {};
  int nkt = qt + 1;

  const __bf16* Kg = Kr + (size_t)kvh * S * 64;
  const __bf16* Vg = Vt + (size_t)kvh * 64 * S;
  int srow8 = lane >> 3;          // row-within-8 of chunk
  int schk = (lane & 7) ^ srow8;  // swizzled in-row 16B-chunk index

#define STAGE(buf, ks)                                                            \
  {                                                                               \
    __bf16* kb = &KV[buf][0][0];                                                  \
    __bf16* vb = &KV[buf][1][0];                                                  \
    _Pragma("unroll") for (int c = 0; c < 2; ++c) {                               \
      int c1kb = w * 2 + c;                                                       \
      int rr = c1kb * 8 + srow8;                                                  \
      int rrg = (rr & 0x23) | ((rr & 0x0C) << 1) | ((rr & 0x10) >> 2);            \
      gload_lds16(Kg + (size_t)((ks) + rrg) * 64 + schk * 8, kb + c1kb * 512);    \
      gload_lds16(Vg + (size_t)rr * S + (ks) + schk * 8, vb + c1kb * 512);        \
    }                                                                             \
  }

  STAGE(0, 0);

  int r7 = lmod & 7;
  int ca = ldiv ^ r7;        // swizzled chunk, k-slots 0..31 half
  int cb = (4 + ldiv) ^ r7;  // k-slots 32..63 half

  int cur = 0;
  for (int kt = 0; kt < nkt; ++kt) {
    int ks = kt * 64;
    __syncthreads();  // drains own gload vmcnt (issued one compute-phase ago)
    if (kt + 1 < nkt) STAGE(cur ^ 1, ks + 64);
    const __bf16* Ksb = &KV[cur][0][0];
    const __bf16* Vsb = &KV[cur][1][0];

    // ---- QK^T (swapped): reg (t16,r) of lane (q=lmod,d=ldiv) holds score for
    // global k = ks + 32*(t16>>1) + 4*(t16&1) + 8*d + r (pi-permuted staging).
    f32x4 st[4] = {};
    __builtin_amdgcn_s_setprio(1);
#pragma unroll
    for (int t16 = 0; t16 < 4; ++t16) {
      int row = t16 * 16 + lmod;
      bf16x8 kf0 = *(const bf16x8*)(Ksb + row * 64 + ca * 8);
      bf16x8 kf1 = *(const bf16x8*)(Ksb + row * 64 + cb * 8);
      st[t16] = MFMA16(kf0, qf0, st[t16]);
      st[t16] = MFMA16(kf1, qf1, st[t16]);
    }
    __builtin_amdgcn_s_setprio(0);

    if (kt == nkt - 1) {  // diagonal tile: causal mask (permuted k formula)
      int qq = R0 + lmod;
#pragma unroll
      for (int t16 = 0; t16 < 4; ++t16) {
        int kk = ks + (t16 >> 1) * 32 + (t16 & 1) * 4 + ldiv * 8;
#pragma unroll
        for (int r = 0; r < 4; ++r)
          st[t16][r] = (kk + r) <= qq ? st[t16][r] : -1e30f;
      }
    }

    // V fragments
    bf16x8 vf[8];
#pragma unroll
    for (int g = 0; g < 4; ++g) {
      int row = g * 16 + lmod;
      vf[g] = *(const bf16x8*)(Vsb + row * 64 + ca * 8);
      vf[4 + g] = *(const bf16x8*)(Vsb + row * 64 + cb * 8);
    }

    // ---- shift-free softmax: p = exp2(st); per-lane partial sums
#pragma unroll
    for (int t16 = 0; t16 < 4; ++t16)
#pragma unroll
      for (int r = 0; r < 4; ++r) {
        float pv = __builtin_amdgcn_exp2f(st[t16][r]);
        st[t16][r] = pv;
        lacc[r] += pv;
      }

    // pack P: registers are already in PV A-fragment order (pi staging)
    u32x4 av0, av1;
    av0[0] = pk2(st[0][0], st[0][1]);
    av0[1] = pk2(st[0][2], st[0][3]);
    av0[2] = pk2(st[1][0], st[1][1]);
    av0[3] = pk2(st[1][2], st[1][3]);
    av1[0] = pk2(st[2][0], st[2][1]);
    av1[1] = pk2(st[2][2], st[2][3]);
    av1[2] = pk2(st[3][0], st[3][1]);
    av1[3] = pk2(st[3][2], st[3][3]);
    bf16x8 pa0 = __builtin_bit_cast(bf16x8, av0);
    bf16x8 pa1 = __builtin_bit_cast(bf16x8, av1);

    __builtin_amdgcn_s_setprio(1);
#pragma unroll
    for (int g = 0; g < 4; ++g) {
      acc[g] = MFMA16(pa0, vf[g], acc[g]);
      acc[g] = MFMA16(pa1, vf[4 + g], acc[g]);
    }
    __builtin_amdgcn_s_setprio(0);
    cur ^= 1;
  }

  // epilogue: reduce l across lanes once, then normalize
  {
    float lsum = lacc[0] + lacc[1] + lacc[2] + lacc[3];
    lsum += __shfl_xor(lsum, 16);
    lsum += __shfl_xor(lsum, 32);
    float linv[4];
#pragma unroll
    for (int r = 0; r < 4; ++r) {
      float lq = __shfl(lsum, ldiv * 4 + r);
      linv[r] = 1.0f / lq;
    }
#pragma unroll
    for (int g = 0; g < 4; ++g)
#pragma unroll
      for (int r = 0; r < 4; ++r)
        O[(size_t)(R0 + ldiv * 4 + r) * 2048 + h * 64 + g * 16 + lmod] =
            (__bf16)(acc[g][r] * linv[r]);
  }
}

// ---------------------------------------------------------------- launch
extern "C" void kernel_launch(void* const* d_in, const int* in_sizes, int n_in,
                              void* d_out, int out_size, void* d_ws, size_t ws_size,
                              hipStream_t stream) {
  const float* x = (const float*)d_in[0];
  const float* cosb = (const float*)d_in[1];
  const float* sinb = (const float*)d_in[2];
  const float* wqkv = (const float*)d_in[3];
  const float* wo = (const float*)d_in[4];
  float* out = (float*)d_out;

  char* ws = (char*)d_ws;
  __bf16* xb    = (__bf16*)(ws + 0);
  __bf16* wqkvT = (__bf16*)(ws + 8388608);
  __bf16* woT   = (__bf16*)(ws + 20971520);
  __bf16* qkvb  = (__bf16*)(ws + 29360128);
  __bf16* Krb   = (__bf16*)(ws + 41943040);
  __bf16* Vtb   = (__bf16*)(ws + 44040192);
  __bf16* attnb = (__bf16*)(ws + 46137344);

  cvt_f32_bf16<<<4096, 256, 0, stream>>>(x, xb);
  transpose_f32_bf16<<<dim3(48, 32), 256, 0, stream>>>(wqkv, wqkvT, 2048, 3072);
  transpose_f32_bf16<<<dim3(32, 32), 256, 0, stream>>>(wo, woT, 2048, 2048);
  gemm4<__bf16><<<dim3(24, 16), 256, 0, stream>>>(xb, wqkvT, qkvb, 2048, 3072, 2048);
  rope_restruct<<<dim3(32, 8), 256, 0, stream>>>(qkvb, cosb, sinb, Krb, Vtb);
  attn_fwd<<<dim3(32, 32), 256, 0, stream>>>(qkvb, Krb, Vtb, attnb);
  gemm4<float><<<dim3(16, 16), 256, 0, stream>>>(attnb, woT, out, 2048, 2048, 2048);
}